// Round 10
// baseline (598.675 us; speedup 1.0000x reference)
//
#include <hip/hip_runtime.h>

#define N_NODES 100000
#define N_EDGES 1600000
#define IN_F 256
#define HID 128
#define OUT_F 48
#define PAD_F 64
#define ALPHA 0.01f
#define K_STEPS 10
#define DROP_SCALE (1.0f / (1.0f + 1e-5f))

#define NBUCK 196      // buckets of 512 rows
#define BCAP 10240     // bucket capacity (mean 8163, 23 sigma headroom)
#define EPB 4096       // edges per bucketing block
#define ROW_MASK_CLR 0xFFFFFFFFFC01FFFFULL  // clears bits 25:17 (local row)

#define MLP_BLOCKS ((N_NODES / 16 + 3) / 4)          // 1563
#define BUCKET_BLOCKS ((N_EDGES + EPB - 1) / EPB)    // 391

typedef __bf16 v8bf __attribute__((ext_vector_type(8)));
typedef float v4f __attribute__((ext_vector_type(4)));
typedef unsigned long long u64;

static __device__ __forceinline__ __bf16 tobf(float f) { return (__bf16)f; }

// ---------------- weight transpose+convert ---------------------------------
__global__ __launch_bounds__(256) void conv_w(const float* __restrict__ W1,
                                              const float* __restrict__ W2,
                                              __bf16* __restrict__ w1t,
                                              __bf16* __restrict__ w2t) {
  int i = blockIdx.x * 256 + threadIdx.x;
  if (i < HID * IN_F) {
    int n = i >> 8, k = i & 255;
    w1t[i] = tobf(W1[k * HID + n]);
  }
  int j = i - HID * IN_F;
  if (j >= 0 && j < OUT_F * HID) {
    int n = j >> 7, k = j & 127;
    w2t[j] = tobf(W2[k * OUT_F + n]);
  }
}

// ---------------- fused: MLP (blocks 0..MLP_BLOCKS-1) + bucket binning -----
__global__ __launch_bounds__(256, 4) void fused_mlp_bucket(
    const float* __restrict__ x, const __bf16* __restrict__ w1t,
    const float* __restrict__ b1, const __bf16* __restrict__ w2t,
    const float* __restrict__ b2, __bf16* __restrict__ h0,
    const int* __restrict__ rows, const int* __restrict__ cols,
    const float* __restrict__ vals, int* __restrict__ bcur,
    u64* __restrict__ brec) {
  __shared__ __bf16 h1s[64][136];  // 17.4 KB (mlp path)
  __shared__ int lhist[NBUCK];     // bucket path
  __shared__ int lbase[NBUCK];

  const int tid = threadIdx.x;

  if (blockIdx.x < MLP_BLOCKS) {
    // ======================= MLP path =======================
    const int wv = tid >> 6;
    const int l = tid & 63;
    const int lm = l & 15;
    const int ko = (l >> 4) * 8;
    const int gw = blockIdx.x * 4 + wv;
    if (gw >= N_NODES / 16) return;
    const int n0w = gw * 16;
    const int xrow = n0w + lm;

    // prefetch the lane's whole x row slice: 16 x float4 = 256B in flight
    const float* xb = x + (size_t)xrow * IN_F + ko;
    float4 xr[16];
#pragma unroll
    for (int k0 = 0; k0 < 8; k0++) {
      xr[2 * k0] = *(const float4*)(xb + k0 * 32);
      xr[2 * k0 + 1] = *(const float4*)(xb + k0 * 32 + 4);
    }
    // pin all 16 loads before any convert/MFMA is scheduled
    __builtin_amdgcn_sched_barrier(0);

    v4f acc1[8];
#pragma unroll
    for (int nf = 0; nf < 8; nf++) acc1[nf] = (v4f){0.f, 0.f, 0.f, 0.f};

#pragma unroll
    for (int k0 = 0; k0 < 8; k0++) {
      const float* f0 = (const float*)&xr[2 * k0];
      v8bf a;
#pragma unroll
      for (int j = 0; j < 8; j++) a[j] = tobf(f0[j]);
      const __bf16* w1base = w1t + (size_t)lm * IN_F + k0 * 32 + ko;
#pragma unroll
      for (int nf = 0; nf < 8; nf++) {
        v8bf b = *(const v8bf*)(w1base + nf * 16 * IN_F);
        acc1[nf] = __builtin_amdgcn_mfma_f32_16x16x32_bf16(a, b, acc1[nf], 0, 0, 0);
      }
    }

    // bias + relu -> h1s. D frag: col=lm, row=(l>>4)*4+q
#pragma unroll
    for (int nf = 0; nf < 8; nf++) {
      float bb = b1[nf * 16 + lm];
#pragma unroll
      for (int q = 0; q < 4; q++) {
        int rr = (wv << 4) + (l >> 4) * 4 + q;
        h1s[rr][nf * 16 + lm] = tobf(fmaxf(acc1[nf][q] + bb, 0.f));
      }
    }
    __syncthreads();

    // layer 2: A from h1s, B straight from global w2t (L2-resident)
    const int lrow = (wv << 4) + lm;
    v4f acc2[3];
#pragma unroll
    for (int nf = 0; nf < 3; nf++) acc2[nf] = (v4f){0.f, 0.f, 0.f, 0.f};
    const __bf16* w2base = w2t + (size_t)lm * HID + ko;
#pragma unroll
    for (int k0 = 0; k0 < 4; k0++) {
      v8bf a = *(const v8bf*)&h1s[lrow][k0 * 32 + ko];
#pragma unroll
      for (int nf = 0; nf < 3; nf++) {
        v8bf b = *(const v8bf*)(w2base + nf * 16 * HID + k0 * 32);
        acc2[nf] = __builtin_amdgcn_mfma_f32_16x16x32_bf16(a, b, acc2[nf], 0, 0, 0);
      }
    }
#pragma unroll
    for (int nf = 0; nf < 3; nf++) {
      float bb = b2[nf * 16 + lm];
#pragma unroll
      for (int q = 0; q < 4; q++) {
        int node = n0w + (l >> 4) * 4 + q;
        h0[(size_t)node * PAD_F + nf * 16 + lm] = tobf(acc2[nf][q] + bb);
      }
    }
    // zero pad cols 48..63
    if (l < 32) {
      uint4 z = make_uint4(0, 0, 0, 0);
      *(uint4*)(h0 + (size_t)(n0w + (l >> 1)) * PAD_F + 48 + (l & 1) * 8) = z;
    }
  } else {
    // ======================= bucket path =======================
    const int bid = blockIdx.x - MLP_BLOCKS;
    const int base = bid * EPB;

    for (int i = tid; i < NBUCK; i += 256) lhist[i] = 0;
    __syncthreads();

    u64 rec[16];
    short bb[16];
    short pp[16];
#pragma unroll
    for (int j = 0; j < 4; j++) {
      int e = base + j * 1024 + tid * 4;
      bool ok = e < N_EDGES;
      int4 r4 = ok ? *(const int4*)(rows + e) : make_int4(0, 0, 0, 0);
      int4 c4 = ok ? *(const int4*)(cols + e) : make_int4(0, 0, 0, 0);
      float4 v4 = ok ? *(const float4*)(vals + e) : make_float4(0, 0, 0, 0);
      int rr[4] = {r4.x, r4.y, r4.z, r4.w};
      int cc[4] = {c4.x, c4.y, c4.z, c4.w};
      float vv[4] = {v4.x, v4.y, v4.z, v4.w};
#pragma unroll
      for (int q = 0; q < 4; q++) {
        int idx = j * 4 + q;
        int b = rr[q] >> 9;
        float v = vv[q] * (DROP_SCALE * (1.0f - ALPHA));
        rec[idx] = ((u64)__float_as_uint(v) << 32) |
                   ((u64)(rr[q] & 511) << 17) | (unsigned)cc[q];
        bb[idx] = ok ? (short)b : (short)-1;
        pp[idx] = ok ? (short)atomicAdd(&lhist[b], 1) : (short)0;
      }
    }
    __syncthreads();

    for (int i = tid; i < NBUCK; i += 256) {
      int n = lhist[i];
      lbase[i] = (n > 0) ? atomicAdd(&bcur[i * 16], n) : 0;
    }
    __syncthreads();

#pragma unroll
    for (int j = 0; j < 16; j++) {
      if (bb[j] >= 0)
        brec[(size_t)bb[j] * BCAP + lbase[bb[j]] + pp[j]] = rec[j];
    }
  }
}

// ---------------- CSR build: bucket-count exclusive scan --------------------
__global__ __launch_bounds__(256) void bscan_kernel(const int* __restrict__ bcur,
                                                    int* __restrict__ bstart,
                                                    int* __restrict__ rowptr) {
  __shared__ int s[256];
  int t = threadIdx.x;
  int v = (t < NBUCK) ? bcur[t * 16] : 0;
  s[t] = v;
  __syncthreads();
  for (int off = 1; off < 256; off <<= 1) {
    int add = (t >= off) ? s[t - off] : 0;
    __syncthreads();
    s[t] += add;
    __syncthreads();
  }
  if (t < NBUCK) bstart[t] = s[t] - v;
  if (t == 0) rowptr[N_NODES] = N_EDGES;
}

// ---------------- CSR build pass 2: per-bucket LDS counting sort ------------
__global__ __launch_bounds__(512) void csr_kernel(
    const int* __restrict__ bcur, const int* __restrict__ bstart,
    const u64* __restrict__ brec, int* __restrict__ rowptr,
    u64* __restrict__ edges) {
  __shared__ int cnt[512];
  __shared__ int sc[512];
  const int b = blockIdx.x;
  const int t = threadIdx.x;
  const int n = bcur[b * 16];
  const int base = bstart[b];
  const size_t boff = (size_t)b * BCAP;

  cnt[t] = 0;
  __syncthreads();
  for (int i = t; i < n; i += 512)
    atomicAdd(&cnt[(int)((brec[boff + i] >> 17) & 511)], 1);
  __syncthreads();

  int v = cnt[t];
  sc[t] = v;
  __syncthreads();
  for (int off = 1; off < 512; off <<= 1) {
    int add = (t >= off) ? sc[t - off] : 0;
    __syncthreads();
    sc[t] += add;
    __syncthreads();
  }
  int excl = sc[t] - v;
  int grow = b * 512 + t;
  if (grow < N_NODES) rowptr[grow] = base + excl;
  cnt[t] = excl;
  __syncthreads();

  for (int i = t; i < n; i += 512) {
    u64 rec = brec[boff + i];
    int rr = (int)((rec >> 17) & 511);
    int p = atomicAdd(&cnt[rr], 1);
    edges[base + p] = rec & ROW_MASK_CLR;
  }
}

// ---------------- propagation: wave/row, 4 edges x 16 lanes (uint2) --------
// 16 lanes x 8B cover one 128B h row; unroll x4 puts a full average row
// (16 edges = 16 lines) in flight in ONE latency round; reduce is only
// 2 shuffle levels x 4 regs.
template <int FINAL>
__global__ __launch_bounds__(256) void prop_kernel(
    const __bf16* __restrict__ hin, __bf16* __restrict__ hout,
    float* __restrict__ fout, const int* __restrict__ rowptr,
    const u64* __restrict__ edges) {
  int wid = (blockIdx.x * 256 + threadIdx.x) >> 6;
  int lane = threadIdx.x & 63;
  if (wid >= N_NODES) return;
  const int eg = lane >> 4;   // edge slot 0..3
  const int fq = lane & 15;   // feature quad: features 4*fq .. 4*fq+3
  int s = __builtin_amdgcn_readfirstlane(rowptr[wid]);
  int e = __builtin_amdgcn_readfirstlane(rowptr[wid + 1]);

  float acc[4] = {0.f, 0.f, 0.f, 0.f};
  if (eg == 0) {
    uint2 q = *(const uint2*)(hin + (size_t)wid * PAD_F + fq * 4);
    acc[0] = ALPHA * __uint_as_float(q.x << 16);
    acc[1] = ALPHA * __uint_as_float(q.x & 0xffff0000u);
    acc[2] = ALPHA * __uint_as_float(q.y << 16);
    acc[3] = ALPHA * __uint_as_float(q.y & 0xffff0000u);
  }

  int i = s;
  for (; i + 16 <= e; i += 16) {
    u64 r[4];
#pragma unroll
    for (int u = 0; u < 4; u++) r[u] = edges[i + u * 4 + eg];
    uint2 q[4];
#pragma unroll
    for (int u = 0; u < 4; u++)
      q[u] = *(const uint2*)(hin + (size_t)(unsigned)(r[u] & 0xffffffffu) * PAD_F +
                             fq * 4);
#pragma unroll
    for (int u = 0; u < 4; u++) {
      float v = __uint_as_float((unsigned)(r[u] >> 32));
      acc[0] = fmaf(v, __uint_as_float(q[u].x << 16), acc[0]);
      acc[1] = fmaf(v, __uint_as_float(q[u].x & 0xffff0000u), acc[1]);
      acc[2] = fmaf(v, __uint_as_float(q[u].y << 16), acc[2]);
      acc[3] = fmaf(v, __uint_as_float(q[u].y & 0xffff0000u), acc[3]);
    }
  }
  for (; i + 4 <= e; i += 4) {
    u64 r = edges[i + eg];
    uint2 q = *(const uint2*)(hin + (size_t)(unsigned)(r & 0xffffffffu) * PAD_F +
                              fq * 4);
    float v = __uint_as_float((unsigned)(r >> 32));
    acc[0] = fmaf(v, __uint_as_float(q.x << 16), acc[0]);
    acc[1] = fmaf(v, __uint_as_float(q.x & 0xffff0000u), acc[1]);
    acc[2] = fmaf(v, __uint_as_float(q.y << 16), acc[2]);
    acc[3] = fmaf(v, __uint_as_float(q.y & 0xffff0000u), acc[3]);
  }
  if (i < e) {  // masked tail: 1..3 edges
    int idx = i + eg;
    u64 r = edges[idx < e ? idx : (e - 1)];
    uint2 q = *(const uint2*)(hin + (size_t)(unsigned)(r & 0xffffffffu) * PAD_F +
                              fq * 4);
    float v = (idx < e) ? __uint_as_float((unsigned)(r >> 32)) : 0.f;
    acc[0] = fmaf(v, __uint_as_float(q.x << 16), acc[0]);
    acc[1] = fmaf(v, __uint_as_float(q.x & 0xffff0000u), acc[1]);
    acc[2] = fmaf(v, __uint_as_float(q.y << 16), acc[2]);
    acc[3] = fmaf(v, __uint_as_float(q.y & 0xffff0000u), acc[3]);
  }

  // reduce across the 4 edge groups
#pragma unroll
  for (int j = 0; j < 4; j++) {
    acc[j] += __shfl_xor(acc[j], 16, 64);
    acc[j] += __shfl_xor(acc[j], 32, 64);
  }

  if (eg == 0) {
    if (FINAL) {
      if (fq < 12) {
        v4f o = {acc[0], acc[1], acc[2], acc[3]};
        __builtin_nontemporal_store(o, (v4f*)(fout + (size_t)wid * OUT_F + fq * 4));
      }
    } else {
      unsigned short b0 = __builtin_bit_cast(unsigned short, (__bf16)acc[0]);
      unsigned short b1 = __builtin_bit_cast(unsigned short, (__bf16)acc[1]);
      unsigned short b2 = __builtin_bit_cast(unsigned short, (__bf16)acc[2]);
      unsigned short b3 = __builtin_bit_cast(unsigned short, (__bf16)acc[3]);
      uint2 w;
      w.x = ((unsigned)b1 << 16) | b0;
      w.y = ((unsigned)b3 << 16) | b2;
      *(uint2*)(hout + (size_t)wid * PAD_F + fq * 4) = w;
    }
  }
}

// ---------------- launch ----------------------------------------------------
extern "C" void kernel_launch(void* const* d_in, const int* in_sizes, int n_in,
                              void* d_out, int out_size, void* d_ws,
                              size_t ws_size, hipStream_t stream) {
  const float* x = (const float*)d_in[0];
  const int* rows = (const int*)d_in[1];
  const int* cols = (const int*)d_in[2];
  const float* vals = (const float*)d_in[3];
  const float* W1 = (const float*)d_in[4];
  const float* b1 = (const float*)d_in[5];
  const float* W2 = (const float*)d_in[6];
  const float* b2 = (const float*)d_in[7];
  float* out = (float*)d_out;

  char* ws = (char*)d_ws;
  const size_t HA_OFF = 0;                  // 12,800,000
  const size_t HB_OFF = 12800000;           // 12,800,000
  const size_t EDGES_OFF = 25600000;        // 12,800,000
  const size_t BREC_OFF = 38400000;         // 196*10240*8 = 16,056,320
  const size_t ROWPTR_OFF = 54456320;       // 400,128
  const size_t BCUR_OFF = 54856448;         // 196*64 = 12,544
  const size_t BSTART_OFF = 54868992;       // 1,024
  const size_t W1T_OFF = 54870016;          // 65,536
  const size_t W2T_OFF = 54935552;          // 12,288

  __bf16* hA = (__bf16*)(ws + HA_OFF);
  __bf16* hB = (__bf16*)(ws + HB_OFF);
  u64* edges = (u64*)(ws + EDGES_OFF);
  u64* brec = (u64*)(ws + BREC_OFF);
  int* rowptr = (int*)(ws + ROWPTR_OFF);
  int* bcur = (int*)(ws + BCUR_OFF);
  int* bstart = (int*)(ws + BSTART_OFF);
  __bf16* w1t = (__bf16*)(ws + W1T_OFF);
  __bf16* w2t = (__bf16*)(ws + W2T_OFF);

  conv_w<<<(HID * IN_F + OUT_F * HID + 255) / 256, 256, 0, stream>>>(W1, W2,
                                                                     w1t, w2t);
  (void)hipMemsetAsync(bcur, 0, NBUCK * 64, stream);

  fused_mlp_bucket<<<MLP_BLOCKS + BUCKET_BLOCKS, 256, 0, stream>>>(
      x, w1t, b1, w2t, b2, hA, rows, cols, vals, bcur, brec);

  bscan_kernel<<<1, 256, 0, stream>>>(bcur, bstart, rowptr);
  csr_kernel<<<NBUCK, 512, 0, stream>>>(bcur, bstart, brec, rowptr, edges);

  const int PROP_BLOCKS = (N_NODES * 64 + 255) / 256;
  for (int k = 0; k < K_STEPS - 1; k++) {
    const __bf16* hin = (k & 1) ? hB : hA;
    __bf16* hout = (k & 1) ? hA : hB;
    prop_kernel<0><<<PROP_BLOCKS, 256, 0, stream>>>(hin, hout, nullptr, rowptr,
                                                    edges);
  }
  prop_kernel<1><<<PROP_BLOCKS, 256, 0, stream>>>(hB, nullptr, out, rowptr,
                                                  edges);
}

// Round 11
// 550.395 us; speedup vs baseline: 1.0877x; 1.0877x over previous
//
#include <hip/hip_runtime.h>

#define N_NODES 100000
#define N_EDGES 1600000
#define IN_F 256
#define HID 128
#define OUT_F 48
#define PAD_F 64
#define ALPHA 0.01f
#define K_STEPS 10
#define DROP_SCALE (1.0f / (1.0f + 1e-5f))

#define NBUCK 196      // buckets of 512 rows
#define BCAP 10240     // bucket capacity (mean 8163, 23 sigma headroom)
#define EPB 4096       // edges per bucketing block
#define ROW_MASK_CLR 0xFFFFFFFFFC01FFFFULL  // clears bits 25:17 (local row)

// fused pre-kernel block ranges
#define XCONV_BLOCKS 6250   // 25.6M elems / (256 thr * 16 elems)
#define CONVW_BLOCKS 153    // (32768 + 6144 + 255)/256
#define BUCKET_BLOCKS 391   // ceil(1.6M / 4096)

typedef __bf16 v8bf __attribute__((ext_vector_type(8)));
typedef float v4f __attribute__((ext_vector_type(4)));
typedef unsigned long long u64;

static __device__ __forceinline__ __bf16 tobf(float f) { return (__bf16)f; }
static __device__ __forceinline__ unsigned pack2(float a, float b) {
  unsigned short lo = __builtin_bit_cast(unsigned short, (__bf16)a);
  unsigned short hi = __builtin_bit_cast(unsigned short, (__bf16)b);
  return ((unsigned)hi << 16) | lo;
}

// ---------------- fused pre-pass: x->bf16 stream + weight conv + bucketing --
// rec u64: val[63:32] | localrow[25:17] | col[16:0]
__global__ __launch_bounds__(256) void fused_pre(
    const float* __restrict__ x, const float* __restrict__ W1,
    const float* __restrict__ W2, __bf16* __restrict__ xb,
    __bf16* __restrict__ w1t, __bf16* __restrict__ w2t,
    const int* __restrict__ rows, const int* __restrict__ cols,
    const float* __restrict__ vals, int* __restrict__ bcur,
    u64* __restrict__ brec) {
  __shared__ int lhist[NBUCK];
  __shared__ int lbase[NBUCK];
  const int tid = threadIdx.x;

  if (blockIdx.x < XCONV_BLOCKS) {
    // ---- x fp32 -> bf16, 16 elems per thread, streaming ----
    int c = blockIdx.x * 256 + tid;  // < 1,600,000 exactly
    const float4* xp = (const float4*)(x + (size_t)c * 16);
    float4 f0 = xp[0], f1 = xp[1], f2 = xp[2], f3 = xp[3];
    uint4 o0 = make_uint4(pack2(f0.x, f0.y), pack2(f0.z, f0.w),
                          pack2(f1.x, f1.y), pack2(f1.z, f1.w));
    uint4 o1 = make_uint4(pack2(f2.x, f2.y), pack2(f2.z, f2.w),
                          pack2(f3.x, f3.y), pack2(f3.z, f3.w));
    uint4* op = (uint4*)(xb + (size_t)c * 16);
    op[0] = o0;
    op[1] = o1;
  } else if (blockIdx.x < XCONV_BLOCKS + CONVW_BLOCKS) {
    // ---- weight transpose+convert ----
    int i = (blockIdx.x - XCONV_BLOCKS) * 256 + tid;
    if (i < HID * IN_F) {
      int n = i >> 8, k = i & 255;
      w1t[i] = tobf(W1[k * HID + n]);
    }
    int j = i - HID * IN_F;
    if (j >= 0 && j < OUT_F * HID) {
      int n = j >> 7, k = j & 127;
      w2t[j] = tobf(W2[k * OUT_F + n]);
    }
  } else {
    // ---- block-aggregated bucket binning ----
    const int bid = blockIdx.x - XCONV_BLOCKS - CONVW_BLOCKS;
    const int base = bid * EPB;

    for (int i = tid; i < NBUCK; i += 256) lhist[i] = 0;
    __syncthreads();

    u64 rec[16];
    short bb[16];
    short pp[16];
#pragma unroll
    for (int j = 0; j < 4; j++) {
      int e = base + j * 1024 + tid * 4;
      bool ok = e < N_EDGES;
      int4 r4 = ok ? *(const int4*)(rows + e) : make_int4(0, 0, 0, 0);
      int4 c4 = ok ? *(const int4*)(cols + e) : make_int4(0, 0, 0, 0);
      float4 v4 = ok ? *(const float4*)(vals + e) : make_float4(0, 0, 0, 0);
      int rr[4] = {r4.x, r4.y, r4.z, r4.w};
      int cc[4] = {c4.x, c4.y, c4.z, c4.w};
      float vv[4] = {v4.x, v4.y, v4.z, v4.w};
#pragma unroll
      for (int q = 0; q < 4; q++) {
        int idx = j * 4 + q;
        int b = rr[q] >> 9;
        float v = vv[q] * (DROP_SCALE * (1.0f - ALPHA));
        rec[idx] = ((u64)__float_as_uint(v) << 32) |
                   ((u64)(rr[q] & 511) << 17) | (unsigned)cc[q];
        bb[idx] = ok ? (short)b : (short)-1;
        pp[idx] = ok ? (short)atomicAdd(&lhist[b], 1) : (short)0;
      }
    }
    __syncthreads();

    for (int i = tid; i < NBUCK; i += 256) {
      int n = lhist[i];
      lbase[i] = (n > 0) ? atomicAdd(&bcur[i * 16], n) : 0;
    }
    __syncthreads();

#pragma unroll
    for (int j = 0; j < 16; j++) {
      if (bb[j] >= 0)
        brec[(size_t)bb[j] * BCAP + lbase[bb[j]] + pp[j]] = rec[j];
    }
  }
}

// ---------------- MLP via MFMA, bf16 x input -> h0 bf16 [N][64] ------------
// A-fragment = one 16B load straight from xb; 8 independent loads per lane.
__global__ __launch_bounds__(256, 4) void mlp_mfma(
    const __bf16* __restrict__ xb, const __bf16* __restrict__ w1t,
    const float* __restrict__ b1, const __bf16* __restrict__ w2t,
    const float* __restrict__ b2, __bf16* __restrict__ h0) {
  __shared__ __bf16 h1s[64][136];  // 17.4 KB

  const int tid = threadIdx.x;
  const int wv = tid >> 6;
  const int l = tid & 63;
  const int lm = l & 15;
  const int ko = (l >> 4) * 8;
  const int gw = blockIdx.x * 4 + wv;
  if (gw >= N_NODES / 16) return;
  const int n0w = gw * 16;
  const int xrow = n0w + lm;

  // prefetch all 8 A-fragments for this lane's row (32 VGPR, no converts)
  const __bf16* xbr = xb + (size_t)xrow * IN_F + ko;
  v8bf a8[8];
#pragma unroll
  for (int k0 = 0; k0 < 8; k0++) a8[k0] = *(const v8bf*)(xbr + k0 * 32);

  v4f acc1[8];
#pragma unroll
  for (int nf = 0; nf < 8; nf++) acc1[nf] = (v4f){0.f, 0.f, 0.f, 0.f};

#pragma unroll
  for (int k0 = 0; k0 < 8; k0++) {
    const __bf16* w1base = w1t + (size_t)lm * IN_F + k0 * 32 + ko;
#pragma unroll
    for (int nf = 0; nf < 8; nf++) {
      v8bf b = *(const v8bf*)(w1base + nf * 16 * IN_F);
      acc1[nf] = __builtin_amdgcn_mfma_f32_16x16x32_bf16(a8[k0], b, acc1[nf], 0, 0, 0);
    }
  }

  // bias + relu -> h1s. D frag: col=lm, row=(l>>4)*4+q
#pragma unroll
  for (int nf = 0; nf < 8; nf++) {
    float bb = b1[nf * 16 + lm];
#pragma unroll
    for (int q = 0; q < 4; q++) {
      int rr = (wv << 4) + (l >> 4) * 4 + q;
      h1s[rr][nf * 16 + lm] = tobf(fmaxf(acc1[nf][q] + bb, 0.f));
    }
  }
  __syncthreads();

  // layer 2: A from h1s, B straight from global w2t (L2-resident)
  const int lrow = (wv << 4) + lm;
  v4f acc2[3];
#pragma unroll
  for (int nf = 0; nf < 3; nf++) acc2[nf] = (v4f){0.f, 0.f, 0.f, 0.f};
  const __bf16* w2base = w2t + (size_t)lm * HID + ko;
#pragma unroll
  for (int k0 = 0; k0 < 4; k0++) {
    v8bf a = *(const v8bf*)&h1s[lrow][k0 * 32 + ko];
#pragma unroll
    for (int nf = 0; nf < 3; nf++) {
      v8bf b = *(const v8bf*)(w2base + nf * 16 * HID + k0 * 32);
      acc2[nf] = __builtin_amdgcn_mfma_f32_16x16x32_bf16(a, b, acc2[nf], 0, 0, 0);
    }
  }
#pragma unroll
  for (int nf = 0; nf < 3; nf++) {
    float bb = b2[nf * 16 + lm];
#pragma unroll
    for (int q = 0; q < 4; q++) {
      int node = n0w + (l >> 4) * 4 + q;
      h0[(size_t)node * PAD_F + nf * 16 + lm] = tobf(acc2[nf][q] + bb);
    }
  }
  // zero pad cols 48..63
  if (l < 32) {
    uint4 z = make_uint4(0, 0, 0, 0);
    *(uint4*)(h0 + (size_t)(n0w + (l >> 1)) * PAD_F + 48 + (l & 1) * 8) = z;
  }
}

// ---------------- CSR build: bucket-count exclusive scan --------------------
__global__ __launch_bounds__(256) void bscan_kernel(const int* __restrict__ bcur,
                                                    int* __restrict__ bstart,
                                                    int* __restrict__ rowptr) {
  __shared__ int s[256];
  int t = threadIdx.x;
  int v = (t < NBUCK) ? bcur[t * 16] : 0;
  s[t] = v;
  __syncthreads();
  for (int off = 1; off < 256; off <<= 1) {
    int add = (t >= off) ? s[t - off] : 0;
    __syncthreads();
    s[t] += add;
    __syncthreads();
  }
  if (t < NBUCK) bstart[t] = s[t] - v;
  if (t == 0) rowptr[N_NODES] = N_EDGES;
}

// ---------------- CSR build pass 2: per-bucket LDS counting sort ------------
__global__ __launch_bounds__(512) void csr_kernel(
    const int* __restrict__ bcur, const int* __restrict__ bstart,
    const u64* __restrict__ brec, int* __restrict__ rowptr,
    u64* __restrict__ edges) {
  __shared__ int cnt[512];
  __shared__ int sc[512];
  const int b = blockIdx.x;
  const int t = threadIdx.x;
  const int n = bcur[b * 16];
  const int base = bstart[b];
  const size_t boff = (size_t)b * BCAP;

  cnt[t] = 0;
  __syncthreads();
  for (int i = t; i < n; i += 512)
    atomicAdd(&cnt[(int)((brec[boff + i] >> 17) & 511)], 1);
  __syncthreads();

  int v = cnt[t];
  sc[t] = v;
  __syncthreads();
  for (int off = 1; off < 512; off <<= 1) {
    int add = (t >= off) ? sc[t - off] : 0;
    __syncthreads();
    sc[t] += add;
    __syncthreads();
  }
  int excl = sc[t] - v;
  int grow = b * 512 + t;
  if (grow < N_NODES) rowptr[grow] = base + excl;
  cnt[t] = excl;
  __syncthreads();

  for (int i = t; i < n; i += 512) {
    u64 rec = brec[boff + i];
    int rr = (int)((rec >> 17) & 511);
    int p = atomicAdd(&cnt[rr], 1);
    edges[base + p] = rec & ROW_MASK_CLR;
  }
}

// ---------------- propagation: wave/row, 8 edges x 8 lanes (dwordx4) -------
template <int FINAL>
__global__ __launch_bounds__(256) void prop_kernel(
    const __bf16* __restrict__ hin, __bf16* __restrict__ hout,
    float* __restrict__ fout, const int* __restrict__ rowptr,
    const u64* __restrict__ edges) {
  int wid = (blockIdx.x * 256 + threadIdx.x) >> 6;
  int lane = threadIdx.x & 63;
  if (wid >= N_NODES) return;
  const int g = lane >> 3;
  const int t = lane & 7;
  int s = __builtin_amdgcn_readfirstlane(rowptr[wid]);
  int e = __builtin_amdgcn_readfirstlane(rowptr[wid + 1]);

  float acc[8];
#pragma unroll
  for (int j = 0; j < 8; j++) acc[j] = 0.f;

  if (g == 0) {
    uint4 q = *(const uint4*)(hin + (size_t)wid * PAD_F + t * 8);
    unsigned uu[4] = {q.x, q.y, q.z, q.w};
#pragma unroll
    for (int k = 0; k < 4; k++) {
      acc[2 * k] = ALPHA * __uint_as_float(uu[k] << 16);
      acc[2 * k + 1] = ALPHA * __uint_as_float(uu[k] & 0xffff0000u);
    }
  }

  int i = s + g;
  for (; i + 8 < e; i += 16) {
    u64 r0 = edges[i];
    u64 r1 = edges[i + 8];
    int c0 = (int)(r0 & 0xffffffffu);
    int c1 = (int)(r1 & 0xffffffffu);
    float v0 = __uint_as_float((unsigned)(r0 >> 32));
    float v1 = __uint_as_float((unsigned)(r1 >> 32));
    uint4 q0 = *(const uint4*)(hin + (size_t)c0 * PAD_F + t * 8);
    uint4 q1 = *(const uint4*)(hin + (size_t)c1 * PAD_F + t * 8);
    unsigned a0[4] = {q0.x, q0.y, q0.z, q0.w};
    unsigned a1[4] = {q1.x, q1.y, q1.z, q1.w};
#pragma unroll
    for (int k = 0; k < 4; k++) {
      acc[2 * k] = fmaf(v0, __uint_as_float(a0[k] << 16), acc[2 * k]);
      acc[2 * k + 1] = fmaf(v0, __uint_as_float(a0[k] & 0xffff0000u), acc[2 * k + 1]);
    }
#pragma unroll
    for (int k = 0; k < 4; k++) {
      acc[2 * k] = fmaf(v1, __uint_as_float(a1[k] << 16), acc[2 * k]);
      acc[2 * k + 1] = fmaf(v1, __uint_as_float(a1[k] & 0xffff0000u), acc[2 * k + 1]);
    }
  }
  if (i < e) {
    u64 r0 = edges[i];
    int c0 = (int)(r0 & 0xffffffffu);
    float v0 = __uint_as_float((unsigned)(r0 >> 32));
    uint4 q0 = *(const uint4*)(hin + (size_t)c0 * PAD_F + t * 8);
    unsigned a0[4] = {q0.x, q0.y, q0.z, q0.w};
#pragma unroll
    for (int k = 0; k < 4; k++) {
      acc[2 * k] = fmaf(v0, __uint_as_float(a0[k] << 16), acc[2 * k]);
      acc[2 * k + 1] = fmaf(v0, __uint_as_float(a0[k] & 0xffff0000u), acc[2 * k + 1]);
    }
  }

#pragma unroll
  for (int m = 8; m <= 32; m <<= 1) {
#pragma unroll
    for (int j = 0; j < 8; j++) acc[j] += __shfl_xor(acc[j], m, 64);
  }

  if (g == 0) {
    if (FINAL) {
      if (t < 6) {
        float* dst = fout + (size_t)wid * OUT_F + t * 8;
        v4f lo4 = {acc[0], acc[1], acc[2], acc[3]};
        v4f hi4 = {acc[4], acc[5], acc[6], acc[7]};
        __builtin_nontemporal_store(lo4, (v4f*)dst);
        __builtin_nontemporal_store(hi4, (v4f*)(dst + 4));
      }
    } else {
      unsigned w[4];
#pragma unroll
      for (int k = 0; k < 4; k++) {
        unsigned short lo = __builtin_bit_cast(unsigned short, (__bf16)acc[2 * k]);
        unsigned short hi = __builtin_bit_cast(unsigned short, (__bf16)acc[2 * k + 1]);
        w[k] = ((unsigned)hi << 16) | lo;
      }
      *(uint4*)(hout + (size_t)wid * PAD_F + t * 8) =
          make_uint4(w[0], w[1], w[2], w[3]);
    }
  }
}

// ---------------- launch ----------------------------------------------------
extern "C" void kernel_launch(void* const* d_in, const int* in_sizes, int n_in,
                              void* d_out, int out_size, void* d_ws,
                              size_t ws_size, hipStream_t stream) {
  const float* x = (const float*)d_in[0];
  const int* rows = (const int*)d_in[1];
  const int* cols = (const int*)d_in[2];
  const float* vals = (const float*)d_in[3];
  const float* W1 = (const float*)d_in[4];
  const float* b1 = (const float*)d_in[5];
  const float* W2 = (const float*)d_in[6];
  const float* b2 = (const float*)d_in[7];
  float* out = (float*)d_out;

  char* ws = (char*)d_ws;
  // xb [0, 51.2M) is dead after mlp_mfma; hB aliases its first 12.8M and
  // edges aliases its second 12.8M (csr/prop launch after mlp, stream-ordered)
  const size_t XB_OFF = 0;                  // 51,200,000 (bf16 x)
  const size_t HB_OFF = 0;                  // 12,800,000 (aliases xb)
  const size_t EDGES_OFF = 12800000;        // 12,800,000 (aliases xb)
  const size_t HA_OFF = 51200000;           // 12,800,000
  const size_t BREC_OFF = 64000000;         // 16,056,320
  const size_t ROWPTR_OFF = 80056320;       // 400,128
  const size_t BCUR_OFF = 80456448;         // 12,544
  const size_t BSTART_OFF = 80469248;       // 1,024
  const size_t W1T_OFF = 80470272;          // 65,536
  const size_t W2T_OFF = 80535808;          // 12,288  -> end 80,548,096

  __bf16* xb = (__bf16*)(ws + XB_OFF);
  __bf16* hA = (__bf16*)(ws + HA_OFF);
  __bf16* hB = (__bf16*)(ws + HB_OFF);
  u64* edges = (u64*)(ws + EDGES_OFF);
  u64* brec = (u64*)(ws + BREC_OFF);
  int* rowptr = (int*)(ws + ROWPTR_OFF);
  int* bcur = (int*)(ws + BCUR_OFF);
  int* bstart = (int*)(ws + BSTART_OFF);
  __bf16* w1t = (__bf16*)(ws + W1T_OFF);
  __bf16* w2t = (__bf16*)(ws + W2T_OFF);

  (void)hipMemsetAsync(bcur, 0, NBUCK * 64, stream);

  fused_pre<<<XCONV_BLOCKS + CONVW_BLOCKS + BUCKET_BLOCKS, 256, 0, stream>>>(
      x, W1, W2, xb, w1t, w2t, rows, cols, vals, bcur, brec);

  mlp_mfma<<<(N_NODES / 16 + 3) / 4, 256, 0, stream>>>(xb, w1t, b1, w2t, b2, hA);

  bscan_kernel<<<1, 256, 0, stream>>>(bcur, bstart, rowptr);
  csr_kernel<<<NBUCK, 512, 0, stream>>>(bcur, bstart, brec, rowptr, edges);

  const int PROP_BLOCKS = (N_NODES * 64 + 255) / 256;
  for (int k = 0; k < K_STEPS - 1; k++) {
    const __bf16* hin = (k & 1) ? hB : hA;
    __bf16* hout = (k & 1) ? hA : hB;
    prop_kernel<0><<<PROP_BLOCKS, 256, 0, stream>>>(hin, hout, nullptr, rowptr,
                                                    edges);
  }
  prop_kernel<1><<<PROP_BLOCKS, 256, 0, stream>>>(hB, nullptr, out, rowptr,
                                                  edges);
}

// Round 12
// 508.136 us; speedup vs baseline: 1.1782x; 1.0832x over previous
//
#include <hip/hip_runtime.h>

#define N_NODES 100000
#define N_EDGES 1600000
#define IN_F 256
#define HID 128
#define OUT_F 48
#define PAD_F 64
#define ALPHA 0.01f
#define K_STEPS 10
#define DROP_SCALE (1.0f / (1.0f + 1e-5f))

#define NBUCK 196      // buckets of 512 rows
#define BCAP 10240     // bucket capacity (mean 8163, 23 sigma headroom)
#define EPB 4096       // edges per bucketing block
#define ROW_MASK_CLR 0xFFFFFFFFFC01FFFFULL  // clears bits 25:17 (local row)

// fused pre-kernel block ranges
#define XCONV_BLOCKS 6250   // 25.6M elems / (256 thr * 16 elems)
#define CONVW_BLOCKS 153    // (32768 + 6144 + 255)/256
#define BUCKET_BLOCKS 391   // ceil(1.6M / 4096)

// fused mlp+csr kernel block ranges
#define MLP2_BLOCKS 782     // ceil(100000 / 128)

typedef __bf16 v8bf __attribute__((ext_vector_type(8)));
typedef float v4f __attribute__((ext_vector_type(4)));
typedef unsigned long long u64;

static __device__ __forceinline__ __bf16 tobf(float f) { return (__bf16)f; }
static __device__ __forceinline__ unsigned pack2(float a, float b) {
  unsigned short lo = __builtin_bit_cast(unsigned short, (__bf16)a);
  unsigned short hi = __builtin_bit_cast(unsigned short, (__bf16)b);
  return ((unsigned)hi << 16) | lo;
}

// ---------------- fused pre-pass: x->bf16 stream + weight conv + bucketing --
// rec u64: val[63:32] | localrow[25:17] | col[16:0]
__global__ __launch_bounds__(256) void fused_pre(
    const float* __restrict__ x, const float* __restrict__ W1,
    const float* __restrict__ W2, __bf16* __restrict__ xb,
    __bf16* __restrict__ w1t, __bf16* __restrict__ w2t,
    const int* __restrict__ rows, const int* __restrict__ cols,
    const float* __restrict__ vals, int* __restrict__ bcur,
    u64* __restrict__ brec) {
  __shared__ int lhist[NBUCK];
  __shared__ int lbase[NBUCK];
  const int tid = threadIdx.x;

  if (blockIdx.x < XCONV_BLOCKS) {
    // ---- x fp32 -> bf16, 16 elems per thread, streaming ----
    int c = blockIdx.x * 256 + tid;  // < 1,600,000 exactly
    const float4* xp = (const float4*)(x + (size_t)c * 16);
    float4 f0 = xp[0], f1 = xp[1], f2 = xp[2], f3 = xp[3];
    uint4 o0 = make_uint4(pack2(f0.x, f0.y), pack2(f0.z, f0.w),
                          pack2(f1.x, f1.y), pack2(f1.z, f1.w));
    uint4 o1 = make_uint4(pack2(f2.x, f2.y), pack2(f2.z, f2.w),
                          pack2(f3.x, f3.y), pack2(f3.z, f3.w));
    uint4* op = (uint4*)(xb + (size_t)c * 16);
    op[0] = o0;
    op[1] = o1;
  } else if (blockIdx.x < XCONV_BLOCKS + CONVW_BLOCKS) {
    // ---- weight transpose+convert ----
    int i = (blockIdx.x - XCONV_BLOCKS) * 256 + tid;
    if (i < HID * IN_F) {
      int n = i >> 8, k = i & 255;
      w1t[i] = tobf(W1[k * HID + n]);
    }
    int j = i - HID * IN_F;
    if (j >= 0 && j < OUT_F * HID) {
      int n = j >> 7, k = j & 127;
      w2t[j] = tobf(W2[k * OUT_F + n]);
    }
  } else {
    // ---- block-aggregated bucket binning ----
    const int bid = blockIdx.x - XCONV_BLOCKS - CONVW_BLOCKS;
    const int base = bid * EPB;

    for (int i = tid; i < NBUCK; i += 256) lhist[i] = 0;
    __syncthreads();

    u64 rec[16];
    short bb[16];
    short pp[16];
#pragma unroll
    for (int j = 0; j < 4; j++) {
      int e = base + j * 1024 + tid * 4;
      bool ok = e < N_EDGES;
      int4 r4 = ok ? *(const int4*)(rows + e) : make_int4(0, 0, 0, 0);
      int4 c4 = ok ? *(const int4*)(cols + e) : make_int4(0, 0, 0, 0);
      float4 v4 = ok ? *(const float4*)(vals + e) : make_float4(0, 0, 0, 0);
      int rr[4] = {r4.x, r4.y, r4.z, r4.w};
      int cc[4] = {c4.x, c4.y, c4.z, c4.w};
      float vv[4] = {v4.x, v4.y, v4.z, v4.w};
#pragma unroll
      for (int q = 0; q < 4; q++) {
        int idx = j * 4 + q;
        int b = rr[q] >> 9;
        float v = vv[q] * (DROP_SCALE * (1.0f - ALPHA));
        rec[idx] = ((u64)__float_as_uint(v) << 32) |
                   ((u64)(rr[q] & 511) << 17) | (unsigned)cc[q];
        bb[idx] = ok ? (short)b : (short)-1;
        pp[idx] = ok ? (short)atomicAdd(&lhist[b], 1) : (short)0;
      }
    }
    __syncthreads();

    for (int i = tid; i < NBUCK; i += 256) {
      int n = lhist[i];
      lbase[i] = (n > 0) ? atomicAdd(&bcur[i * 16], n) : 0;
    }
    __syncthreads();

#pragma unroll
    for (int j = 0; j < 16; j++) {
      if (bb[j] >= 0)
        brec[(size_t)bb[j] * BCAP + lbase[bb[j]] + pp[j]] = rec[j];
    }
  }
}

// ---------------- fused: MLP (LDS-staged weights) + CSR counting sort -------
// MLP blocks: 512 thr = 8 waves, 128 rows/block; w1t (64KB) + w2t (12KB)
// staged ONCE per block into padded LDS -> b-frags at LDS speed, L2 weight
// traffic 400MB -> 50MB. CSR blocks ride in the same dispatch.
__global__ __launch_bounds__(512, 2) void fused_mlp_csr(
    const __bf16* __restrict__ xb, const __bf16* __restrict__ w1t,
    const float* __restrict__ b1, const __bf16* __restrict__ w2t,
    const float* __restrict__ b2, __bf16* __restrict__ h0,
    const int* __restrict__ bcur, const int* __restrict__ bstart_unused,
    const u64* __restrict__ brec, int* __restrict__ rowptr,
    u64* __restrict__ edges) {
  __shared__ __bf16 w1s[128][264];  // 67.6 KB (+8 pad: 2-way banks max)
  __shared__ __bf16 h1s[128][136];  // 34.8 KB
  __shared__ __bf16 w2s[48][136];   // 13.1 KB
  __shared__ int bs[256];
  __shared__ int cnt[512];
  __shared__ int sc[512];

  const int tid = threadIdx.x;

  if (blockIdx.x < MLP2_BLOCKS) {
    // ======================= MLP path =======================
    const int wv = tid >> 6;
    const int l = tid & 63;
    const int lm = l & 15;
    const int ko = (l >> 4) * 8;
    const int n0 = blockIdx.x * 128;
    const int nw = n0 + wv * 16;
    const int xrow = nw + lm;

    // A-frag prefetch (8 independent 16B loads; overruns past row 100000
    // read scratch garbage, results discarded by store guards)
    const __bf16* xbr = xb + (size_t)xrow * IN_F + ko;
    v8bf a8[8];
#pragma unroll
    for (int k0 = 0; k0 < 8; k0++) a8[k0] = *(const v8bf*)(xbr + k0 * 32);

    // stage w1t: 4096 16B chunks; w2t: 768 chunks
    const uint4* w1src = (const uint4*)w1t;
    for (int i = tid; i < 4096; i += 512)
      *(uint4*)&w1s[i >> 5][(i & 31) * 8] = w1src[i];
    const uint4* w2src = (const uint4*)w2t;
    for (int i = tid; i < 768; i += 512)
      *(uint4*)&w2s[i >> 4][(i & 15) * 8] = w2src[i];
    __syncthreads();

    // layer 1: per wave [16 x 256] @ [256 x 128], B from LDS
    v4f acc1[8];
#pragma unroll
    for (int nf = 0; nf < 8; nf++) acc1[nf] = (v4f){0.f, 0.f, 0.f, 0.f};
#pragma unroll
    for (int k0 = 0; k0 < 8; k0++) {
#pragma unroll
      for (int nf = 0; nf < 8; nf++) {
        v8bf b = *(const v8bf*)&w1s[nf * 16 + lm][k0 * 32 + ko];
        acc1[nf] = __builtin_amdgcn_mfma_f32_16x16x32_bf16(a8[k0], b, acc1[nf], 0, 0, 0);
      }
    }

    // bias + relu -> h1s. D frag: col=lm, row=(l>>4)*4+q
#pragma unroll
    for (int nf = 0; nf < 8; nf++) {
      float bb = b1[nf * 16 + lm];
#pragma unroll
      for (int q = 0; q < 4; q++) {
        int rr = wv * 16 + (l >> 4) * 4 + q;
        h1s[rr][nf * 16 + lm] = tobf(fmaxf(acc1[nf][q] + bb, 0.f));
      }
    }
    __syncthreads();

    // layer 2: A from h1s, B from w2s (LDS)
    const int lrow = wv * 16 + lm;
    v4f acc2[3];
#pragma unroll
    for (int nf = 0; nf < 3; nf++) acc2[nf] = (v4f){0.f, 0.f, 0.f, 0.f};
#pragma unroll
    for (int k0 = 0; k0 < 4; k0++) {
      v8bf a = *(const v8bf*)&h1s[lrow][k0 * 32 + ko];
#pragma unroll
      for (int nf = 0; nf < 3; nf++) {
        v8bf b = *(const v8bf*)&w2s[nf * 16 + lm][k0 * 32 + ko];
        acc2[nf] = __builtin_amdgcn_mfma_f32_16x16x32_bf16(a, b, acc2[nf], 0, 0, 0);
      }
    }
#pragma unroll
    for (int nf = 0; nf < 3; nf++) {
      float bb = b2[nf * 16 + lm];
#pragma unroll
      for (int q = 0; q < 4; q++) {
        int node = nw + (l >> 4) * 4 + q;
        if (node < N_NODES)
          h0[(size_t)node * PAD_F + nf * 16 + lm] = tobf(acc2[nf][q] + bb);
      }
    }
    // zero pad cols 48..63: 128 rows x 4 uint2 chunks = 512 = blockDim
    {
      int row = tid >> 2, chunk = tid & 3;
      int node = n0 + row;
      if (node < N_NODES) {
        uint2 z = make_uint2(0, 0);
        *(uint2*)(h0 + (size_t)node * PAD_F + 48 + chunk * 4) = z;
      }
    }
  } else {
    // ======================= CSR path =======================
    const int b = blockIdx.x - MLP2_BLOCKS;
    const int t = tid;

    // inline exclusive prefix over bucket counts (196 entries)
    if (t < 256) bs[t] = (t < NBUCK) ? bcur[t * 16] : 0;
    __syncthreads();
    for (int off = 1; off < 256; off <<= 1) {
      int add = (t < 256 && t >= off) ? bs[t - off] : 0;
      __syncthreads();
      if (t < 256) bs[t] += add;
      __syncthreads();
    }
    const int n = bcur[b * 16];
    const int base = bs[b] - n;  // exclusive
    const size_t boff = (size_t)b * BCAP;
    if (b == 0 && t == 0) rowptr[N_NODES] = N_EDGES;

    cnt[t] = 0;
    __syncthreads();
    for (int i = t; i < n; i += 512)
      atomicAdd(&cnt[(int)((brec[boff + i] >> 17) & 511)], 1);
    __syncthreads();

    int v = cnt[t];
    sc[t] = v;
    __syncthreads();
    for (int off = 1; off < 512; off <<= 1) {
      int add = (t >= off) ? sc[t - off] : 0;
      __syncthreads();
      sc[t] += add;
      __syncthreads();
    }
    int excl = sc[t] - v;
    int grow = b * 512 + t;
    if (grow < N_NODES) rowptr[grow] = base + excl;
    cnt[t] = excl;
    __syncthreads();

    for (int i = t; i < n; i += 512) {
      u64 rec = brec[boff + i];
      int rr = (int)((rec >> 17) & 511);
      int p = atomicAdd(&cnt[rr], 1);
      edges[base + p] = rec & ROW_MASK_CLR;
    }
  }
}

// ---------------- propagation: wave/row, 8 edges x 8 lanes (dwordx4) -------
template <int FINAL>
__global__ __launch_bounds__(256) void prop_kernel(
    const __bf16* __restrict__ hin, __bf16* __restrict__ hout,
    float* __restrict__ fout, const int* __restrict__ rowptr,
    const u64* __restrict__ edges) {
  int wid = (blockIdx.x * 256 + threadIdx.x) >> 6;
  int lane = threadIdx.x & 63;
  if (wid >= N_NODES) return;
  const int g = lane >> 3;
  const int t = lane & 7;
  int s = __builtin_amdgcn_readfirstlane(rowptr[wid]);
  int e = __builtin_amdgcn_readfirstlane(rowptr[wid + 1]);

  float acc[8];
#pragma unroll
  for (int j = 0; j < 8; j++) acc[j] = 0.f;

  if (g == 0) {
    uint4 q = *(const uint4*)(hin + (size_t)wid * PAD_F + t * 8);
    unsigned uu[4] = {q.x, q.y, q.z, q.w};
#pragma unroll
    for (int k = 0; k < 4; k++) {
      acc[2 * k] = ALPHA * __uint_as_float(uu[k] << 16);
      acc[2 * k + 1] = ALPHA * __uint_as_float(uu[k] & 0xffff0000u);
    }
  }

  int i = s + g;
  for (; i + 8 < e; i += 16) {
    u64 r0 = edges[i];
    u64 r1 = edges[i + 8];
    int c0 = (int)(r0 & 0xffffffffu);
    int c1 = (int)(r1 & 0xffffffffu);
    float v0 = __uint_as_float((unsigned)(r0 >> 32));
    float v1 = __uint_as_float((unsigned)(r1 >> 32));
    uint4 q0 = *(const uint4*)(hin + (size_t)c0 * PAD_F + t * 8);
    uint4 q1 = *(const uint4*)(hin + (size_t)c1 * PAD_F + t * 8);
    unsigned a0[4] = {q0.x, q0.y, q0.z, q0.w};
    unsigned a1[4] = {q1.x, q1.y, q1.z, q1.w};
#pragma unroll
    for (int k = 0; k < 4; k++) {
      acc[2 * k] = fmaf(v0, __uint_as_float(a0[k] << 16), acc[2 * k]);
      acc[2 * k + 1] = fmaf(v0, __uint_as_float(a0[k] & 0xffff0000u), acc[2 * k + 1]);
    }
#pragma unroll
    for (int k = 0; k < 4; k++) {
      acc[2 * k] = fmaf(v1, __uint_as_float(a1[k] << 16), acc[2 * k]);
      acc[2 * k + 1] = fmaf(v1, __uint_as_float(a1[k] & 0xffff0000u), acc[2 * k + 1]);
    }
  }
  if (i < e) {
    u64 r0 = edges[i];
    int c0 = (int)(r0 & 0xffffffffu);
    float v0 = __uint_as_float((unsigned)(r0 >> 32));
    uint4 q0 = *(const uint4*)(hin + (size_t)c0 * PAD_F + t * 8);
    unsigned a0[4] = {q0.x, q0.y, q0.z, q0.w};
#pragma unroll
    for (int k = 0; k < 4; k++) {
      acc[2 * k] = fmaf(v0, __uint_as_float(a0[k] << 16), acc[2 * k]);
      acc[2 * k + 1] = fmaf(v0, __uint_as_float(a0[k] & 0xffff0000u), acc[2 * k + 1]);
    }
  }

#pragma unroll
  for (int m = 8; m <= 32; m <<= 1) {
#pragma unroll
    for (int j = 0; j < 8; j++) acc[j] += __shfl_xor(acc[j], m, 64);
  }

  if (g == 0) {
    if (FINAL) {
      if (t < 6) {
        float* dst = fout + (size_t)wid * OUT_F + t * 8;
        v4f lo4 = {acc[0], acc[1], acc[2], acc[3]};
        v4f hi4 = {acc[4], acc[5], acc[6], acc[7]};
        __builtin_nontemporal_store(lo4, (v4f*)dst);
        __builtin_nontemporal_store(hi4, (v4f*)(dst + 4));
      }
    } else {
      unsigned w[4];
#pragma unroll
      for (int k = 0; k < 4; k++) {
        unsigned short lo = __builtin_bit_cast(unsigned short, (__bf16)acc[2 * k]);
        unsigned short hi = __builtin_bit_cast(unsigned short, (__bf16)acc[2 * k + 1]);
        w[k] = ((unsigned)hi << 16) | lo;
      }
      *(uint4*)(hout + (size_t)wid * PAD_F + t * 8) =
          make_uint4(w[0], w[1], w[2], w[3]);
    }
  }
}

// ---------------- launch ----------------------------------------------------
extern "C" void kernel_launch(void* const* d_in, const int* in_sizes, int n_in,
                              void* d_out, int out_size, void* d_ws,
                              size_t ws_size, hipStream_t stream) {
  const float* x = (const float*)d_in[0];
  const int* rows = (const int*)d_in[1];
  const int* cols = (const int*)d_in[2];
  const float* vals = (const float*)d_in[3];
  const float* W1 = (const float*)d_in[4];
  const float* b1 = (const float*)d_in[5];
  const float* W2 = (const float*)d_in[6];
  const float* b2 = (const float*)d_in[7];
  float* out = (float*)d_out;

  char* ws = (char*)d_ws;
  // xb [0, 51.2M) is dead after fused_mlp_csr's mlp blocks; hB and edges
  // alias it (all consumers launch after, stream-ordered). NOTE: edges is
  // written by csr blocks of fused_mlp_csr while mlp blocks read xb — the
  // aliased ranges are disjoint in time? NO — they run concurrently, so
  // edges must NOT alias xb. edges gets its own region; hB (first used by
  // prop step 0 output, after the fused kernel completes) may alias xb.
  const size_t XB_OFF = 0;                  // 51,200,000 (bf16 x)
  const size_t HB_OFF = 0;                  // 12,800,000 (aliases xb - safe)
  const size_t HA_OFF = 51200000;           // 12,800,000
  const size_t EDGES_OFF = 64000000;        // 12,800,000
  const size_t BREC_OFF = 76800000;         // 16,056,320
  const size_t ROWPTR_OFF = 92856320;       // 400,128
  const size_t BCUR_OFF = 93256448;         // 12,544
  const size_t BSTART_OFF = 93268992;       // 1,024
  const size_t W1T_OFF = 93270016;          // 65,536
  const size_t W2T_OFF = 93335552;          // 12,288  -> end 93,347,840

  __bf16* xb = (__bf16*)(ws + XB_OFF);
  __bf16* hA = (__bf16*)(ws + HA_OFF);
  __bf16* hB = (__bf16*)(ws + HB_OFF);
  u64* edges = (u64*)(ws + EDGES_OFF);
  u64* brec = (u64*)(ws + BREC_OFF);
  int* rowptr = (int*)(ws + ROWPTR_OFF);
  int* bcur = (int*)(ws + BCUR_OFF);
  int* bstart = (int*)(ws + BSTART_OFF);
  __bf16* w1t = (__bf16*)(ws + W1T_OFF);
  __bf16* w2t = (__bf16*)(ws + W2T_OFF);

  (void)hipMemsetAsync(bcur, 0, NBUCK * 64, stream);

  fused_pre<<<XCONV_BLOCKS + CONVW_BLOCKS + BUCKET_BLOCKS, 256, 0, stream>>>(
      x, W1, W2, xb, w1t, w2t, rows, cols, vals, bcur, brec);

  fused_mlp_csr<<<MLP2_BLOCKS + NBUCK, 512, 0, stream>>>(
      xb, w1t, b1, w2t, b2, hA, bcur, bstart, brec, rowptr, edges);

  const int PROP_BLOCKS = (N_NODES * 64 + 255) / 256;
  for (int k = 0; k < K_STEPS - 1; k++) {
    const __bf16* hin = (k & 1) ? hB : hA;
    __bf16* hout = (k & 1) ? hA : hB;
    prop_kernel<0><<<PROP_BLOCKS, 256, 0, stream>>>(hin, hout, nullptr, rowptr,
                                                    edges);
  }
  prop_kernel<1><<<PROP_BLOCKS, 256, 0, stream>>>(hB, nullptr, out, rowptr,
                                                  edges);
}

// Round 13
// 495.140 us; speedup vs baseline: 1.2091x; 1.0262x over previous
//
#include <hip/hip_runtime.h>

#define N_NODES 100000
#define N_EDGES 1600000
#define IN_F 256
#define HID 128
#define OUT_F 48
#define PAD_F 64
#define ALPHA 0.01f
#define K_STEPS 10
#define DROP_SCALE (1.0f / (1.0f + 1e-5f))

#define NBUCK 196      // buckets of 512 rows
#define BCAP 10240     // bucket capacity (mean 8163, 23 sigma headroom)
#define EPB 4096       // edges per bucketing block
#define ROW_MASK_CLR 0xFFFFFFFFFC01FFFFULL  // clears bits 25:17 (local row)

// fused pre-kernel block ranges (bucket first: most work, starts earliest)
#define BUCKET_BLOCKS 391   // ceil(1.6M / 4096)
#define CONVW_BLOCKS 153    // (32768 + 6144 + 255)/256

// fused mlp+csr kernel block ranges
#define MLP2_BLOCKS 782     // ceil(100000 / 128)

typedef __bf16 v8bf __attribute__((ext_vector_type(8)));
typedef float v4f __attribute__((ext_vector_type(4)));
typedef unsigned long long u64;

static __device__ __forceinline__ __bf16 tobf(float f) { return (__bf16)f; }

// ---------------- fused pre-pass: bucket binning + weight conv --------------
// rec u64: val[63:32] | localrow[25:17] | col[16:0]
__global__ __launch_bounds__(256) void fused_pre(
    const float* __restrict__ W1, const float* __restrict__ W2,
    __bf16* __restrict__ w1t, __bf16* __restrict__ w2t,
    const int* __restrict__ rows, const int* __restrict__ cols,
    const float* __restrict__ vals, int* __restrict__ bcur,
    u64* __restrict__ brec) {
  __shared__ int lhist[NBUCK];
  __shared__ int lbase[NBUCK];
  const int tid = threadIdx.x;

  if (blockIdx.x < BUCKET_BLOCKS) {
    // ---- block-aggregated bucket binning ----
    const int base = blockIdx.x * EPB;

    for (int i = tid; i < NBUCK; i += 256) lhist[i] = 0;
    __syncthreads();

    u64 rec[16];
    short bb[16];
    short pp[16];
#pragma unroll
    for (int j = 0; j < 4; j++) {
      int e = base + j * 1024 + tid * 4;
      bool ok = e < N_EDGES;
      int4 r4 = ok ? *(const int4*)(rows + e) : make_int4(0, 0, 0, 0);
      int4 c4 = ok ? *(const int4*)(cols + e) : make_int4(0, 0, 0, 0);
      float4 v4 = ok ? *(const float4*)(vals + e) : make_float4(0, 0, 0, 0);
      int rr[4] = {r4.x, r4.y, r4.z, r4.w};
      int cc[4] = {c4.x, c4.y, c4.z, c4.w};
      float vv[4] = {v4.x, v4.y, v4.z, v4.w};
#pragma unroll
      for (int q = 0; q < 4; q++) {
        int idx = j * 4 + q;
        int b = rr[q] >> 9;
        float v = vv[q] * (DROP_SCALE * (1.0f - ALPHA));
        rec[idx] = ((u64)__float_as_uint(v) << 32) |
                   ((u64)(rr[q] & 511) << 17) | (unsigned)cc[q];
        bb[idx] = ok ? (short)b : (short)-1;
        pp[idx] = ok ? (short)atomicAdd(&lhist[b], 1) : (short)0;
      }
    }
    __syncthreads();

    for (int i = tid; i < NBUCK; i += 256) {
      int n = lhist[i];
      lbase[i] = (n > 0) ? atomicAdd(&bcur[i * 16], n) : 0;
    }
    __syncthreads();

#pragma unroll
    for (int j = 0; j < 16; j++) {
      if (bb[j] >= 0)
        brec[(size_t)bb[j] * BCAP + lbase[bb[j]] + pp[j]] = rec[j];
    }
  } else {
    // ---- weight transpose+convert ----
    int i = (blockIdx.x - BUCKET_BLOCKS) * 256 + tid;
    if (i < HID * IN_F) {
      int n = i >> 8, k = i & 255;
      w1t[i] = tobf(W1[k * HID + n]);
    }
    int j = i - HID * IN_F;
    if (j >= 0 && j < OUT_F * HID) {
      int n = j >> 7, k = j & 127;
      w2t[j] = tobf(W2[k * OUT_F + n]);
    }
  }
}

// ---------------- fused: MLP (LDS weights, fp32 x direct) + CSR sort --------
// MLP blocks: 512 thr; x row prefetched as 16 float4 (issued BEFORE weight
// staging so HBM latency overlaps the LDS fill). 1 block/CU (115KB LDS) ->
// launch_bounds(512,2) gives 256-VGPR budget, prefetch stays in registers.
__global__ __launch_bounds__(512, 2) void fused_mlp_csr(
    const float* __restrict__ x, const __bf16* __restrict__ w1t,
    const float* __restrict__ b1, const __bf16* __restrict__ w2t,
    const float* __restrict__ b2, __bf16* __restrict__ h0,
    const int* __restrict__ bcur, const u64* __restrict__ brec,
    int* __restrict__ rowptr, u64* __restrict__ edges) {
  __shared__ __bf16 w1s[128][264];  // 67.6 KB (+8 pad)
  __shared__ __bf16 h1s[128][136];  // 34.8 KB
  __shared__ __bf16 w2s[48][136];   // 13.1 KB
  __shared__ int bs[256];
  __shared__ int cnt[512];
  __shared__ int sc[512];

  const int tid = threadIdx.x;

  if (blockIdx.x < MLP2_BLOCKS) {
    // ======================= MLP path =======================
    const int wv = tid >> 6;
    const int l = tid & 63;
    const int lm = l & 15;
    const int ko = (l >> 4) * 8;
    const int n0 = blockIdx.x * 128;
    const int nw = n0 + wv * 16;
    const int xrow = nw + lm;
    const int xrc = (xrow < N_NODES) ? xrow : (N_NODES - 1);  // clamp ragged

    // issue the full fp32 A-row prefetch first: 16 independent 16B loads
    const float* xrp = x + (size_t)xrc * IN_F + ko;
    float4 xf[16];
#pragma unroll
    for (int k0 = 0; k0 < 8; k0++) {
      xf[2 * k0] = *(const float4*)(xrp + k0 * 32);
      xf[2 * k0 + 1] = *(const float4*)(xrp + k0 * 32 + 4);
    }

    // stage w1t / w2t into LDS (overlaps the x loads above)
    const uint4* w1src = (const uint4*)w1t;
    for (int i = tid; i < 4096; i += 512)
      *(uint4*)&w1s[i >> 5][(i & 31) * 8] = w1src[i];
    const uint4* w2src = (const uint4*)w2t;
    for (int i = tid; i < 768; i += 512)
      *(uint4*)&w2s[i >> 4][(i & 15) * 8] = w2src[i];
    __syncthreads();

    // convert prefetched fp32 -> bf16 A-frags
    v8bf a8[8];
#pragma unroll
    for (int k0 = 0; k0 < 8; k0++) {
      const float* f0 = (const float*)&xf[2 * k0];
#pragma unroll
      for (int j = 0; j < 8; j++) a8[k0][j] = tobf(f0[j]);
    }

    // layer 1: per wave [16 x 256] @ [256 x 128], B from LDS
    v4f acc1[8];
#pragma unroll
    for (int nf = 0; nf < 8; nf++) acc1[nf] = (v4f){0.f, 0.f, 0.f, 0.f};
#pragma unroll
    for (int k0 = 0; k0 < 8; k0++) {
#pragma unroll
      for (int nf = 0; nf < 8; nf++) {
        v8bf b = *(const v8bf*)&w1s[nf * 16 + lm][k0 * 32 + ko];
        acc1[nf] = __builtin_amdgcn_mfma_f32_16x16x32_bf16(a8[k0], b, acc1[nf], 0, 0, 0);
      }
    }

    // bias + relu -> h1s. D frag: col=lm, row=(l>>4)*4+q
#pragma unroll
    for (int nf = 0; nf < 8; nf++) {
      float bb = b1[nf * 16 + lm];
#pragma unroll
      for (int q = 0; q < 4; q++) {
        int rr = wv * 16 + (l >> 4) * 4 + q;
        h1s[rr][nf * 16 + lm] = tobf(fmaxf(acc1[nf][q] + bb, 0.f));
      }
    }
    __syncthreads();

    // layer 2: A from h1s, B from w2s (LDS)
    const int lrow = wv * 16 + lm;
    v4f acc2[3];
#pragma unroll
    for (int nf = 0; nf < 3; nf++) acc2[nf] = (v4f){0.f, 0.f, 0.f, 0.f};
#pragma unroll
    for (int k0 = 0; k0 < 4; k0++) {
      v8bf a = *(const v8bf*)&h1s[lrow][k0 * 32 + ko];
#pragma unroll
      for (int nf = 0; nf < 3; nf++) {
        v8bf b = *(const v8bf*)&w2s[nf * 16 + lm][k0 * 32 + ko];
        acc2[nf] = __builtin_amdgcn_mfma_f32_16x16x32_bf16(a, b, acc2[nf], 0, 0, 0);
      }
    }
#pragma unroll
    for (int nf = 0; nf < 3; nf++) {
      float bb = b2[nf * 16 + lm];
#pragma unroll
      for (int q = 0; q < 4; q++) {
        int node = nw + (l >> 4) * 4 + q;
        if (node < N_NODES)
          h0[(size_t)node * PAD_F + nf * 16 + lm] = tobf(acc2[nf][q] + bb);
      }
    }
    // zero pad cols 48..63: 128 rows x 4 uint2 chunks = 512 = blockDim
    {
      int row = tid >> 2, chunk = tid & 3;
      int node = n0 + row;
      if (node < N_NODES) {
        uint2 z = make_uint2(0, 0);
        *(uint2*)(h0 + (size_t)node * PAD_F + 48 + chunk * 4) = z;
      }
    }
  } else {
    // ======================= CSR path =======================
    const int b = blockIdx.x - MLP2_BLOCKS;
    const int t = tid;

    // inline exclusive prefix over bucket counts (196 entries)
    if (t < 256) bs[t] = (t < NBUCK) ? bcur[t * 16] : 0;
    __syncthreads();
    for (int off = 1; off < 256; off <<= 1) {
      int add = (t < 256 && t >= off) ? bs[t - off] : 0;
      __syncthreads();
      if (t < 256) bs[t] += add;
      __syncthreads();
    }
    const int n = bcur[b * 16];
    const int base = bs[b] - n;  // exclusive
    const size_t boff = (size_t)b * BCAP;
    if (b == 0 && t == 0) rowptr[N_NODES] = N_EDGES;

    cnt[t] = 0;
    __syncthreads();
    for (int i = t; i < n; i += 512)
      atomicAdd(&cnt[(int)((brec[boff + i] >> 17) & 511)], 1);
    __syncthreads();

    int v = cnt[t];
    sc[t] = v;
    __syncthreads();
    for (int off = 1; off < 512; off <<= 1) {
      int add = (t >= off) ? sc[t - off] : 0;
      __syncthreads();
      sc[t] += add;
      __syncthreads();
    }
    int excl = sc[t] - v;
    int grow = b * 512 + t;
    if (grow < N_NODES) rowptr[grow] = base + excl;
    cnt[t] = excl;
    __syncthreads();

    for (int i = t; i < n; i += 512) {
      u64 rec = brec[boff + i];
      int rr = (int)((rec >> 17) & 511);
      int p = atomicAdd(&cnt[rr], 1);
      edges[base + p] = rec & ROW_MASK_CLR;
    }
  }
}

// ---------------- propagation: wave/row, 8 edges x 8 lanes (dwordx4) -------
template <int FINAL>
__global__ __launch_bounds__(256) void prop_kernel(
    const __bf16* __restrict__ hin, __bf16* __restrict__ hout,
    float* __restrict__ fout, const int* __restrict__ rowptr,
    const u64* __restrict__ edges) {
  int wid = (blockIdx.x * 256 + threadIdx.x) >> 6;
  int lane = threadIdx.x & 63;
  if (wid >= N_NODES) return;
  const int g = lane >> 3;
  const int t = lane & 7;
  int s = __builtin_amdgcn_readfirstlane(rowptr[wid]);
  int e = __builtin_amdgcn_readfirstlane(rowptr[wid + 1]);

  float acc[8];
#pragma unroll
  for (int j = 0; j < 8; j++) acc[j] = 0.f;

  if (g == 0) {
    uint4 q = *(const uint4*)(hin + (size_t)wid * PAD_F + t * 8);
    unsigned uu[4] = {q.x, q.y, q.z, q.w};
#pragma unroll
    for (int k = 0; k < 4; k++) {
      acc[2 * k] = ALPHA * __uint_as_float(uu[k] << 16);
      acc[2 * k + 1] = ALPHA * __uint_as_float(uu[k] & 0xffff0000u);
    }
  }

  int i = s + g;
  for (; i + 8 < e; i += 16) {
    u64 r0 = edges[i];
    u64 r1 = edges[i + 8];
    int c0 = (int)(r0 & 0xffffffffu);
    int c1 = (int)(r1 & 0xffffffffu);
    float v0 = __uint_as_float((unsigned)(r0 >> 32));
    float v1 = __uint_as_float((unsigned)(r1 >> 32));
    uint4 q0 = *(const uint4*)(hin + (size_t)c0 * PAD_F + t * 8);
    uint4 q1 = *(const uint4*)(hin + (size_t)c1 * PAD_F + t * 8);
    unsigned a0[4] = {q0.x, q0.y, q0.z, q0.w};
    unsigned a1[4] = {q1.x, q1.y, q1.z, q1.w};
#pragma unroll
    for (int k = 0; k < 4; k++) {
      acc[2 * k] = fmaf(v0, __uint_as_float(a0[k] << 16), acc[2 * k]);
      acc[2 * k + 1] = fmaf(v0, __uint_as_float(a0[k] & 0xffff0000u), acc[2 * k + 1]);
    }
#pragma unroll
    for (int k = 0; k < 4; k++) {
      acc[2 * k] = fmaf(v1, __uint_as_float(a1[k] << 16), acc[2 * k]);
      acc[2 * k + 1] = fmaf(v1, __uint_as_float(a1[k] & 0xffff0000u), acc[2 * k + 1]);
    }
  }
  if (i < e) {
    u64 r0 = edges[i];
    int c0 = (int)(r0 & 0xffffffffu);
    float v0 = __uint_as_float((unsigned)(r0 >> 32));
    uint4 q0 = *(const uint4*)(hin + (size_t)c0 * PAD_F + t * 8);
    unsigned a0[4] = {q0.x, q0.y, q0.z, q0.w};
#pragma unroll
    for (int k = 0; k < 4; k++) {
      acc[2 * k] = fmaf(v0, __uint_as_float(a0[k] << 16), acc[2 * k]);
      acc[2 * k + 1] = fmaf(v0, __uint_as_float(a0[k] & 0xffff0000u), acc[2 * k + 1]);
    }
  }

#pragma unroll
  for (int m = 8; m <= 32; m <<= 1) {
#pragma unroll
    for (int j = 0; j < 8; j++) acc[j] += __shfl_xor(acc[j], m, 64);
  }

  if (g == 0) {
    if (FINAL) {
      if (t < 6) {
        float* dst = fout + (size_t)wid * OUT_F + t * 8;
        v4f lo4 = {acc[0], acc[1], acc[2], acc[3]};
        v4f hi4 = {acc[4], acc[5], acc[6], acc[7]};
        __builtin_nontemporal_store(lo4, (v4f*)dst);
        __builtin_nontemporal_store(hi4, (v4f*)(dst + 4));
      }
    } else {
      unsigned w[4];
#pragma unroll
      for (int k = 0; k < 4; k++) {
        unsigned short lo = __builtin_bit_cast(unsigned short, (__bf16)acc[2 * k]);
        unsigned short hi = __builtin_bit_cast(unsigned short, (__bf16)acc[2 * k + 1]);
        w[k] = ((unsigned)hi << 16) | lo;
      }
      *(uint4*)(hout + (size_t)wid * PAD_F + t * 8) =
          make_uint4(w[0], w[1], w[2], w[3]);
    }
  }
}

// ---------------- launch ----------------------------------------------------
extern "C" void kernel_launch(void* const* d_in, const int* in_sizes, int n_in,
                              void* d_out, int out_size, void* d_ws,
                              size_t ws_size, hipStream_t stream) {
  const float* x = (const float*)d_in[0];
  const int* rows = (const int*)d_in[1];
  const int* cols = (const int*)d_in[2];
  const float* vals = (const float*)d_in[3];
  const float* W1 = (const float*)d_in[4];
  const float* b1 = (const float*)d_in[5];
  const float* W2 = (const float*)d_in[6];
  const float* b2 = (const float*)d_in[7];
  float* out = (float*)d_out;

  char* ws = (char*)d_ws;
  const size_t HB_OFF = 0;                  // 12,800,000
  const size_t HA_OFF = 12800000;           // 12,800,000
  const size_t EDGES_OFF = 25600000;        // 12,800,000
  const size_t BREC_OFF = 38400000;         // 16,056,320
  const size_t ROWPTR_OFF = 54456320;       // 400,128
  const size_t BCUR_OFF = 54856448;         // 12,544
  const size_t W1T_OFF = 54870016;          // 65,536
  const size_t W2T_OFF = 54935552;          // 12,288  -> end 54,947,840

  __bf16* hA = (__bf16*)(ws + HA_OFF);
  __bf16* hB = (__bf16*)(ws + HB_OFF);
  u64* edges = (u64*)(ws + EDGES_OFF);
  u64* brec = (u64*)(ws + BREC_OFF);
  int* rowptr = (int*)(ws + ROWPTR_OFF);
  int* bcur = (int*)(ws + BCUR_OFF);
  __bf16* w1t = (__bf16*)(ws + W1T_OFF);
  __bf16* w2t = (__bf16*)(ws + W2T_OFF);

  (void)hipMemsetAsync(bcur, 0, NBUCK * 64, stream);

  fused_pre<<<BUCKET_BLOCKS + CONVW_BLOCKS, 256, 0, stream>>>(
      W1, W2, w1t, w2t, rows, cols, vals, bcur, brec);

  fused_mlp_csr<<<MLP2_BLOCKS + NBUCK, 512, 0, stream>>>(
      x, w1t, b1, w2t, b2, hA, bcur, brec, rowptr, edges);

  const int PROP_BLOCKS = (N_NODES * 64 + 255) / 256;
  for (int k = 0; k < K_STEPS - 1; k++) {
    const __bf16* hin = (k & 1) ? hB : hA;
    __bf16* hout = (k & 1) ? hA : hB;
    prop_kernel<0><<<PROP_BLOCKS, 256, 0, stream>>>(hin, hout, nullptr, rowptr,
                                                    edges);
  }
  prop_kernel<1><<<PROP_BLOCKS, 256, 0, stream>>>(hB, nullptr, out, rowptr,
                                                  edges);
}

// Round 14
// 495.000 us; speedup vs baseline: 1.2094x; 1.0003x over previous
//
#include <hip/hip_runtime.h>

#define N_NODES 100000
#define N_EDGES 1600000
#define IN_F 256
#define HID 128
#define OUT_F 48
#define PAD_F 64
#define ALPHA 0.01f
#define K_STEPS 10
#define DROP_SCALE (1.0f / (1.0f + 1e-5f))

#define NBUCK 196      // buckets of 512 rows
#define BCAP 10240     // bucket capacity (mean 8163, 23 sigma headroom)
#define EPB 4096       // edges per bucketing block
#define ROW_MASK_CLR 0xFFFFFFFFFC01FFFFULL  // clears bits 25:17 (local row)

#define MLP2_BLOCKS 782     // ceil(100000 / 128), 128 rows per 512-thr block
#define BUCKET_BLOCKS 391   // ceil(1.6M / 4096)

typedef __bf16 v8bf __attribute__((ext_vector_type(8)));
typedef float v4f __attribute__((ext_vector_type(4)));
typedef unsigned long long u64;

static __device__ __forceinline__ __bf16 tobf(float f) { return (__bf16)f; }

// ---------------- weight transpose+convert (tiny, runs first) ---------------
__global__ __launch_bounds__(256) void conv_w(const float* __restrict__ W1,
                                              const float* __restrict__ W2,
                                              __bf16* __restrict__ w1t,
                                              __bf16* __restrict__ w2t) {
  int i = blockIdx.x * 256 + threadIdx.x;
  if (i < HID * IN_F) {
    int n = i >> 8, k = i & 255;
    w1t[i] = tobf(W1[k * HID + n]);
  }
  int j = i - HID * IN_F;
  if (j >= 0 && j < OUT_F * HID) {
    int n = j >> 7, k = j & 127;
    w2t[j] = tobf(W2[k * OUT_F + n]);
  }
}

// ---------------- fused: MLP (LDS weights, asm-pinned x prefetch) + bucket --
__global__ __launch_bounds__(512, 2) void fused_mlp_bucket(
    const float* __restrict__ x, const __bf16* __restrict__ w1t,
    const float* __restrict__ b1, const __bf16* __restrict__ w2t,
    const float* __restrict__ b2, __bf16* __restrict__ h0,
    const int* __restrict__ rows, const int* __restrict__ cols,
    const float* __restrict__ vals, int* __restrict__ bcur,
    u64* __restrict__ brec) {
  __shared__ __bf16 w1s[128][264];  // 67.6 KB (+8 pad)
  __shared__ __bf16 h1s[128][136];  // 34.8 KB
  __shared__ __bf16 w2s[48][136];   // 13.1 KB
  __shared__ int lhist[NBUCK];
  __shared__ int lbase[NBUCK];

  const int tid = threadIdx.x;

  if (blockIdx.x < MLP2_BLOCKS) {
    // ======================= MLP path =======================
    const int wv = tid >> 6;
    const int l = tid & 63;
    const int lm = l & 15;
    const int ko = (l >> 4) * 8;
    const int n0 = blockIdx.x * 128;
    const int nw = n0 + wv * 16;
    const int xrow = nw + lm;
    const int xrc = (xrow < N_NODES) ? xrow : (N_NODES - 1);  // clamp ragged

    // issue the full fp32 A-row prefetch: 16 independent 16B loads
    const float* xrp = x + (size_t)xrc * IN_F + ko;
    v4f xf[16];
#pragma unroll
    for (int k0 = 0; k0 < 8; k0++) {
      xf[2 * k0] = *(const v4f*)(xrp + k0 * 32);
      xf[2 * k0 + 1] = *(const v4f*)(xrp + k0 * 32 + 4);
    }

    // stage w1t / w2t into LDS (overlaps the in-flight x loads)
    const uint4* w1src = (const uint4*)w1t;
    for (int i = tid; i < 4096; i += 512)
      *(uint4*)&w1s[i >> 5][(i & 31) * 8] = w1src[i];
    const uint4* w2src = (const uint4*)w2t;
    for (int i = tid; i < 768; i += 512)
      *(uint4*)&w2s[i >> 4][(i & 15) * 8] = w2src[i];
    __syncthreads();

    // asm data-dependence: pins all 16 loads ABOVE this point, uses below.
    // (sched_barrier failed here: IR-level sinking ignores it; "+v" cannot
    // be bypassed.)
#pragma unroll
    for (int i = 0; i < 16; i++) asm volatile("" : "+v"(xf[i]));

    // convert prefetched fp32 -> bf16 A-frags
    v8bf a8[8];
#pragma unroll
    for (int k0 = 0; k0 < 8; k0++) {
#pragma unroll
      for (int j = 0; j < 8; j++) a8[k0][j] = tobf(xf[2 * k0 + (j >> 2)][j & 3]);
    }

    // layer 1: per wave [16 x 256] @ [256 x 128], B from LDS
    v4f acc1[8];
#pragma unroll
    for (int nf = 0; nf < 8; nf++) acc1[nf] = (v4f){0.f, 0.f, 0.f, 0.f};
#pragma unroll
    for (int k0 = 0; k0 < 8; k0++) {
#pragma unroll
      for (int nf = 0; nf < 8; nf++) {
        v8bf b = *(const v8bf*)&w1s[nf * 16 + lm][k0 * 32 + ko];
        acc1[nf] = __builtin_amdgcn_mfma_f32_16x16x32_bf16(a8[k0], b, acc1[nf], 0, 0, 0);
      }
    }

    // bias + relu -> h1s. D frag: col=lm, row=(l>>4)*4+q
#pragma unroll
    for (int nf = 0; nf < 8; nf++) {
      float bb = b1[nf * 16 + lm];
#pragma unroll
      for (int q = 0; q < 4; q++) {
        int rr = wv * 16 + (l >> 4) * 4 + q;
        h1s[rr][nf * 16 + lm] = tobf(fmaxf(acc1[nf][q] + bb, 0.f));
      }
    }
    __syncthreads();

    // layer 2: A from h1s, B from w2s (LDS)
    const int lrow = wv * 16 + lm;
    v4f acc2[3];
#pragma unroll
    for (int nf = 0; nf < 3; nf++) acc2[nf] = (v4f){0.f, 0.f, 0.f, 0.f};
#pragma unroll
    for (int k0 = 0; k0 < 4; k0++) {
      v8bf a = *(const v8bf*)&h1s[lrow][k0 * 32 + ko];
#pragma unroll
      for (int nf = 0; nf < 3; nf++) {
        v8bf b = *(const v8bf*)&w2s[nf * 16 + lm][k0 * 32 + ko];
        acc2[nf] = __builtin_amdgcn_mfma_f32_16x16x32_bf16(a, b, acc2[nf], 0, 0, 0);
      }
    }
#pragma unroll
    for (int nf = 0; nf < 3; nf++) {
      float bb = b2[nf * 16 + lm];
#pragma unroll
      for (int q = 0; q < 4; q++) {
        int node = nw + (l >> 4) * 4 + q;
        if (node < N_NODES)
          h0[(size_t)node * PAD_F + nf * 16 + lm] = tobf(acc2[nf][q] + bb);
      }
    }
    // zero pad cols 48..63: 128 rows x 4 uint2 chunks = 512 = blockDim
    {
      int row = tid >> 2, chunk = tid & 3;
      int node = n0 + row;
      if (node < N_NODES) {
        uint2 z = make_uint2(0, 0);
        *(uint2*)(h0 + (size_t)node * PAD_F + 48 + chunk * 4) = z;
      }
    }
  } else {
    // ======================= bucket path (512 thr, 8 edges/thr) =============
    const int bid = blockIdx.x - MLP2_BLOCKS;
    const int base = bid * EPB;

    for (int i = tid; i < NBUCK; i += 512) lhist[i] = 0;
    __syncthreads();

    u64 rec[8];
    short bb[8];
    short pp[8];
#pragma unroll
    for (int j = 0; j < 2; j++) {
      int e = base + j * 2048 + tid * 4;
      bool ok = e < N_EDGES;
      int4 r4 = ok ? *(const int4*)(rows + e) : make_int4(0, 0, 0, 0);
      int4 c4 = ok ? *(const int4*)(cols + e) : make_int4(0, 0, 0, 0);
      float4 v4 = ok ? *(const float4*)(vals + e) : make_float4(0, 0, 0, 0);
      int rr[4] = {r4.x, r4.y, r4.z, r4.w};
      int cc[4] = {c4.x, c4.y, c4.z, c4.w};
      float vv[4] = {v4.x, v4.y, v4.z, v4.w};
#pragma unroll
      for (int q = 0; q < 4; q++) {
        int idx = j * 4 + q;
        int b = rr[q] >> 9;
        float v = vv[q] * (DROP_SCALE * (1.0f - ALPHA));
        rec[idx] = ((u64)__float_as_uint(v) << 32) |
                   ((u64)(rr[q] & 511) << 17) | (unsigned)cc[q];
        bb[idx] = ok ? (short)b : (short)-1;
        pp[idx] = ok ? (short)atomicAdd(&lhist[b], 1) : (short)0;
      }
    }
    __syncthreads();

    for (int i = tid; i < NBUCK; i += 512) {
      int n = lhist[i];
      lbase[i] = (n > 0) ? atomicAdd(&bcur[i * 16], n) : 0;
    }
    __syncthreads();

#pragma unroll
    for (int j = 0; j < 8; j++) {
      if (bb[j] >= 0)
        brec[(size_t)bb[j] * BCAP + lbase[bb[j]] + pp[j]] = rec[j];
    }
  }
}

// ---------------- CSR: per-bucket LDS counting sort (inline bucket scan) ----
__global__ __launch_bounds__(512) void csr_kernel(
    const int* __restrict__ bcur, const u64* __restrict__ brec,
    int* __restrict__ rowptr, u64* __restrict__ edges) {
  __shared__ int bs[256];
  __shared__ int cnt[512];
  __shared__ int sc[512];
  const int b = blockIdx.x;
  const int t = threadIdx.x;

  // inline exclusive prefix over bucket counts (196 entries)
  if (t < 256) bs[t] = (t < NBUCK) ? bcur[t * 16] : 0;
  __syncthreads();
  for (int off = 1; off < 256; off <<= 1) {
    int add = (t < 256 && t >= off) ? bs[t - off] : 0;
    __syncthreads();
    if (t < 256) bs[t] += add;
    __syncthreads();
  }
  const int n = bcur[b * 16];
  const int base = bs[b] - n;  // exclusive
  const size_t boff = (size_t)b * BCAP;
  if (b == 0 && t == 0) rowptr[N_NODES] = N_EDGES;

  cnt[t] = 0;
  __syncthreads();
  for (int i = t; i < n; i += 512)
    atomicAdd(&cnt[(int)((brec[boff + i] >> 17) & 511)], 1);
  __syncthreads();

  int v = cnt[t];
  sc[t] = v;
  __syncthreads();
  for (int off = 1; off < 512; off <<= 1) {
    int add = (t >= off) ? sc[t - off] : 0;
    __syncthreads();
    sc[t] += add;
    __syncthreads();
  }
  int excl = sc[t] - v;
  int grow = b * 512 + t;
  if (grow < N_NODES) rowptr[grow] = base + excl;
  cnt[t] = excl;
  __syncthreads();

  for (int i = t; i < n; i += 512) {
    u64 rec = brec[boff + i];
    int rr = (int)((rec >> 17) & 511);
    int p = atomicAdd(&cnt[rr], 1);
    edges[base + p] = rec & ROW_MASK_CLR;
  }
}

// ---------------- propagation: wave/row, 8 edges x 8 lanes (dwordx4) -------
template <int FINAL>
__global__ __launch_bounds__(256) void prop_kernel(
    const __bf16* __restrict__ hin, __bf16* __restrict__ hout,
    float* __restrict__ fout, const int* __restrict__ rowptr,
    const u64* __restrict__ edges) {
  int wid = (blockIdx.x * 256 + threadIdx.x) >> 6;
  int lane = threadIdx.x & 63;
  if (wid >= N_NODES) return;
  const int g = lane >> 3;
  const int t = lane & 7;
  int s = __builtin_amdgcn_readfirstlane(rowptr[wid]);
  int e = __builtin_amdgcn_readfirstlane(rowptr[wid + 1]);

  float acc[8];
#pragma unroll
  for (int j = 0; j < 8; j++) acc[j] = 0.f;

  if (g == 0) {
    uint4 q = *(const uint4*)(hin + (size_t)wid * PAD_F + t * 8);
    unsigned uu[4] = {q.x, q.y, q.z, q.w};
#pragma unroll
    for (int k = 0; k < 4; k++) {
      acc[2 * k] = ALPHA * __uint_as_float(uu[k] << 16);
      acc[2 * k + 1] = ALPHA * __uint_as_float(uu[k] & 0xffff0000u);
    }
  }

  int i = s + g;
  for (; i + 8 < e; i += 16) {
    u64 r0 = edges[i];
    u64 r1 = edges[i + 8];
    int c0 = (int)(r0 & 0xffffffffu);
    int c1 = (int)(r1 & 0xffffffffu);
    float v0 = __uint_as_float((unsigned)(r0 >> 32));
    float v1 = __uint_as_float((unsigned)(r1 >> 32));
    uint4 q0 = *(const uint4*)(hin + (size_t)c0 * PAD_F + t * 8);
    uint4 q1 = *(const uint4*)(hin + (size_t)c1 * PAD_F + t * 8);
    unsigned a0[4] = {q0.x, q0.y, q0.z, q0.w};
    unsigned a1[4] = {q1.x, q1.y, q1.z, q1.w};
#pragma unroll
    for (int k = 0; k < 4; k++) {
      acc[2 * k] = fmaf(v0, __uint_as_float(a0[k] << 16), acc[2 * k]);
      acc[2 * k + 1] = fmaf(v0, __uint_as_float(a0[k] & 0xffff0000u), acc[2 * k + 1]);
    }
#pragma unroll
    for (int k = 0; k < 4; k++) {
      acc[2 * k] = fmaf(v1, __uint_as_float(a1[k] << 16), acc[2 * k]);
      acc[2 * k + 1] = fmaf(v1, __uint_as_float(a1[k] & 0xffff0000u), acc[2 * k + 1]);
    }
  }
  if (i < e) {
    u64 r0 = edges[i];
    int c0 = (int)(r0 & 0xffffffffu);
    float v0 = __uint_as_float((unsigned)(r0 >> 32));
    uint4 q0 = *(const uint4*)(hin + (size_t)c0 * PAD_F + t * 8);
    unsigned a0[4] = {q0.x, q0.y, q0.z, q0.w};
#pragma unroll
    for (int k = 0; k < 4; k++) {
      acc[2 * k] = fmaf(v0, __uint_as_float(a0[k] << 16), acc[2 * k]);
      acc[2 * k + 1] = fmaf(v0, __uint_as_float(a0[k] & 0xffff0000u), acc[2 * k + 1]);
    }
  }

#pragma unroll
  for (int m = 8; m <= 32; m <<= 1) {
#pragma unroll
    for (int j = 0; j < 8; j++) acc[j] += __shfl_xor(acc[j], m, 64);
  }

  if (g == 0) {
    if (FINAL) {
      if (t < 6) {
        float* dst = fout + (size_t)wid * OUT_F + t * 8;
        v4f lo4 = {acc[0], acc[1], acc[2], acc[3]};
        v4f hi4 = {acc[4], acc[5], acc[6], acc[7]};
        __builtin_nontemporal_store(lo4, (v4f*)dst);
        __builtin_nontemporal_store(hi4, (v4f*)(dst + 4));
      }
    } else {
      unsigned w[4];
#pragma unroll
      for (int k = 0; k < 4; k++) {
        unsigned short lo = __builtin_bit_cast(unsigned short, (__bf16)acc[2 * k]);
        unsigned short hi = __builtin_bit_cast(unsigned short, (__bf16)acc[2 * k + 1]);
        w[k] = ((unsigned)hi << 16) | lo;
      }
      *(uint4*)(hout + (size_t)wid * PAD_F + t * 8) =
          make_uint4(w[0], w[1], w[2], w[3]);
    }
  }
}

// ---------------- launch ----------------------------------------------------
extern "C" void kernel_launch(void* const* d_in, const int* in_sizes, int n_in,
                              void* d_out, int out_size, void* d_ws,
                              size_t ws_size, hipStream_t stream) {
  const float* x = (const float*)d_in[0];
  const int* rows = (const int*)d_in[1];
  const int* cols = (const int*)d_in[2];
  const float* vals = (const float*)d_in[3];
  const float* W1 = (const float*)d_in[4];
  const float* b1 = (const float*)d_in[5];
  const float* W2 = (const float*)d_in[6];
  const float* b2 = (const float*)d_in[7];
  float* out = (float*)d_out;

  char* ws = (char*)d_ws;
  const size_t HB_OFF = 0;                  // 12,800,000
  const size_t HA_OFF = 12800000;           // 12,800,000
  const size_t EDGES_OFF = 25600000;        // 12,800,000
  const size_t BREC_OFF = 38400000;         // 16,056,320
  const size_t ROWPTR_OFF = 54456320;       // 400,128
  const size_t BCUR_OFF = 54856448;         // 12,544
  const size_t W1T_OFF = 54870016;          // 65,536
  const size_t W2T_OFF = 54935552;          // 12,288  -> end 54,947,840

  __bf16* hA = (__bf16*)(ws + HA_OFF);
  __bf16* hB = (__bf16*)(ws + HB_OFF);
  u64* edges = (u64*)(ws + EDGES_OFF);
  u64* brec = (u64*)(ws + BREC_OFF);
  int* rowptr = (int*)(ws + ROWPTR_OFF);
  int* bcur = (int*)(ws + BCUR_OFF);
  __bf16* w1t = (__bf16*)(ws + W1T_OFF);
  __bf16* w2t = (__bf16*)(ws + W2T_OFF);

  (void)hipMemsetAsync(bcur, 0, NBUCK * 64, stream);
  conv_w<<<(HID * IN_F + OUT_F * HID + 255) / 256, 256, 0, stream>>>(W1, W2,
                                                                     w1t, w2t);

  fused_mlp_bucket<<<MLP2_BLOCKS + BUCKET_BLOCKS, 512, 0, stream>>>(
      x, w1t, b1, w2t, b2, hA, rows, cols, vals, bcur, brec);

  csr_kernel<<<NBUCK, 512, 0, stream>>>(bcur, brec, rowptr, edges);

  const int PROP_BLOCKS = (N_NODES * 64 + 255) / 256;
  for (int k = 0; k < K_STEPS - 1; k++) {
    const __bf16* hin = (k & 1) ? hB : hA;
    __bf16* hout = (k & 1) ? hA : hB;
    prop_kernel<0><<<PROP_BLOCKS, 256, 0, stream>>>(hin, hout, nullptr, rowptr,
                                                    edges);
  }
  prop_kernel<1><<<PROP_BLOCKS, 256, 0, stream>>>(hB, nullptr, out, rowptr,
                                                  edges);
}

// Round 15
// 492.677 us; speedup vs baseline: 1.2151x; 1.0047x over previous
//
#include <hip/hip_runtime.h>

#define N_NODES 100000
#define N_EDGES 1600000
#define IN_F 256
#define HID 128
#define OUT_F 48
#define PAD_F 64
#define ALPHA 0.01f
#define K_STEPS 10
#define DROP_SCALE (1.0f / (1.0f + 1e-5f))

#define NBUCK 196      // buckets of 512 rows
#define BCAP 10240     // bucket capacity (mean 8163, 23 sigma headroom)
#define EPB 4096       // edges per bucketing block
#define ROW_MASK_CLR 0xFFFFFFFFFC01FFFFULL  // clears bits 25:17 (local row)

#define BUCKET_BLOCKS 391   // ceil(1.6M / 4096)
#define CONVW_BLOCKS 153    // (32768 + 6144 + 255)/256
#define MLP2_BLOCKS 782     // ceil(100000 / 128), 128 rows per 512-thr block

typedef __bf16 v8bf __attribute__((ext_vector_type(8)));
typedef float v4f __attribute__((ext_vector_type(4)));
typedef unsigned long long u64;

static __device__ __forceinline__ __bf16 tobf(float f) { return (__bf16)f; }

// ---------------- dispatch 1: bucket binning + weight conv ------------------
// rec u64: val[63:32] | localrow[25:17] | col[16:0]
__global__ __launch_bounds__(256) void pre_kernel(
    const float* __restrict__ W1, const float* __restrict__ W2,
    __bf16* __restrict__ w1t, __bf16* __restrict__ w2t,
    const int* __restrict__ rows, const int* __restrict__ cols,
    const float* __restrict__ vals, int* __restrict__ bcur,
    u64* __restrict__ brec) {
  __shared__ int lhist[NBUCK];
  __shared__ int lbase[NBUCK];
  const int tid = threadIdx.x;

  if (blockIdx.x < BUCKET_BLOCKS) {
    const int base = blockIdx.x * EPB;

    for (int i = tid; i < NBUCK; i += 256) lhist[i] = 0;
    __syncthreads();

    u64 rec[16];
    short bb[16];
    short pp[16];
#pragma unroll
    for (int j = 0; j < 4; j++) {
      int e = base + j * 1024 + tid * 4;
      bool ok = e < N_EDGES;
      int4 r4 = ok ? *(const int4*)(rows + e) : make_int4(0, 0, 0, 0);
      int4 c4 = ok ? *(const int4*)(cols + e) : make_int4(0, 0, 0, 0);
      float4 v4 = ok ? *(const float4*)(vals + e) : make_float4(0, 0, 0, 0);
      int rr[4] = {r4.x, r4.y, r4.z, r4.w};
      int cc[4] = {c4.x, c4.y, c4.z, c4.w};
      float vv[4] = {v4.x, v4.y, v4.z, v4.w};
#pragma unroll
      for (int q = 0; q < 4; q++) {
        int idx = j * 4 + q;
        int b = rr[q] >> 9;
        float v = vv[q] * (DROP_SCALE * (1.0f - ALPHA));
        rec[idx] = ((u64)__float_as_uint(v) << 32) |
                   ((u64)(rr[q] & 511) << 17) | (unsigned)cc[q];
        bb[idx] = ok ? (short)b : (short)-1;
        pp[idx] = ok ? (short)atomicAdd(&lhist[b], 1) : (short)0;
      }
    }
    __syncthreads();

    for (int i = tid; i < NBUCK; i += 256) {
      int n = lhist[i];
      lbase[i] = (n > 0) ? atomicAdd(&bcur[i * 16], n) : 0;
    }
    __syncthreads();

#pragma unroll
    for (int j = 0; j < 16; j++) {
      if (bb[j] >= 0)
        brec[(size_t)bb[j] * BCAP + lbase[bb[j]] + pp[j]] = rec[j];
    }
  } else {
    // ---- weight transpose+convert ----
    int i = (blockIdx.x - BUCKET_BLOCKS) * 256 + tid;
    if (i < HID * IN_F) {
      int n = i >> 8, k = i & 255;
      w1t[i] = tobf(W1[k * HID + n]);
    }
    int j = i - HID * IN_F;
    if (j >= 0 && j < OUT_F * HID) {
      int n = j >> 7, k = j & 127;
      w2t[j] = tobf(W2[k * OUT_F + n]);
    }
  }
}

// ---------------- dispatch 2: MLP (K-split LDS weights, 2 blk/CU) + CSR -----
__global__ __launch_bounds__(512, 4) void fused_mlp_csr(
    const float* __restrict__ x, const __bf16* __restrict__ w1t,
    const float* __restrict__ b1, const __bf16* __restrict__ w2t,
    const float* __restrict__ b2, __bf16* __restrict__ h0,
    const int* __restrict__ bcur, const u64* __restrict__ brec,
    int* __restrict__ rowptr, u64* __restrict__ edges) {
  __shared__ __bf16 w1s[128][136];  // 34.8 KB (one K-half of W1^T, +8 pad)
  __shared__ __bf16 h1s[128][136];  // 34.8 KB
  __shared__ int bs[256];
  __shared__ int cnt[512];
  __shared__ int sc[512];
  // total ~74.7 KB -> 2 blocks/CU

  const int tid = threadIdx.x;

  if (blockIdx.x < MLP2_BLOCKS) {
    // ======================= MLP path =======================
    const int wv = tid >> 6;
    const int l = tid & 63;
    const int lm = l & 15;
    const int ko = (l >> 4) * 8;
    const int n0 = blockIdx.x * 128;
    const int nw = n0 + wv * 16;
    const int xrow = nw + lm;
    const int xrc = (xrow < N_NODES) ? xrow : (N_NODES - 1);  // clamp ragged
    const float* xrp = x + (size_t)xrc * IN_F + ko;
    const uint4* w1src = (const uint4*)w1t;

    v4f acc1[8];
#pragma unroll
    for (int nf = 0; nf < 8; nf++) acc1[nf] = (v4f){0.f, 0.f, 0.f, 0.f};

#pragma unroll
    for (int kh = 0; kh < 2; kh++) {
      // issue this half's x loads (8 independent 16B loads)
      v4f xf[8];
#pragma unroll
      for (int k0 = 0; k0 < 4; k0++) {
        const float* p = xrp + kh * 128 + k0 * 32;
        xf[2 * k0] = *(const v4f*)p;
        xf[2 * k0 + 1] = *(const v4f*)(p + 4);
      }
      // stage this K-half of w1t: 2048 x 16B (overlaps x loads)
      for (int i = tid; i < 2048; i += 512)
        *(uint4*)&w1s[i >> 4][(i & 15) * 8] = w1src[(i >> 4) * 32 + kh * 16 + (i & 15)];
      __syncthreads();

      // convert + MFMA this half
#pragma unroll
      for (int k0 = 0; k0 < 4; k0++) {
        v8bf a;
#pragma unroll
        for (int j = 0; j < 8; j++) a[j] = tobf(xf[2 * k0 + (j >> 2)][j & 3]);
#pragma unroll
        for (int nf = 0; nf < 8; nf++) {
          v8bf b = *(const v8bf*)&w1s[nf * 16 + lm][k0 * 32 + ko];
          acc1[nf] = __builtin_amdgcn_mfma_f32_16x16x32_bf16(a, b, acc1[nf], 0, 0, 0);
        }
      }
      __syncthreads();  // w1s fully consumed before restage
    }

    // bias + relu -> h1s. D frag: col=lm, row=(l>>4)*4+q
#pragma unroll
    for (int nf = 0; nf < 8; nf++) {
      float bb = b1[nf * 16 + lm];
#pragma unroll
      for (int q = 0; q < 4; q++) {
        int rr = wv * 16 + (l >> 4) * 4 + q;
        h1s[rr][nf * 16 + lm] = tobf(fmaxf(acc1[nf][q] + bb, 0.f));
      }
    }
    __syncthreads();

    // layer 2: A from h1s, B straight from global w2t (L2-resident, 12 KB)
    const int lrow = wv * 16 + lm;
    v4f acc2[3];
#pragma unroll
    for (int nf = 0; nf < 3; nf++) acc2[nf] = (v4f){0.f, 0.f, 0.f, 0.f};
    const __bf16* w2base = w2t + (size_t)lm * HID + ko;
#pragma unroll
    for (int k0 = 0; k0 < 4; k0++) {
      v8bf a = *(const v8bf*)&h1s[lrow][k0 * 32 + ko];
#pragma unroll
      for (int nf = 0; nf < 3; nf++) {
        v8bf b = *(const v8bf*)(w2base + nf * 16 * HID + k0 * 32);
        acc2[nf] = __builtin_amdgcn_mfma_f32_16x16x32_bf16(a, b, acc2[nf], 0, 0, 0);
      }
    }
#pragma unroll
    for (int nf = 0; nf < 3; nf++) {
      float bb = b2[nf * 16 + lm];
#pragma unroll
      for (int q = 0; q < 4; q++) {
        int node = nw + (l >> 4) * 4 + q;
        if (node < N_NODES)
          h0[(size_t)node * PAD_F + nf * 16 + lm] = tobf(acc2[nf][q] + bb);
      }
    }
    // zero pad cols 48..63: 128 rows x 4 uint2 chunks = 512 = blockDim
    {
      int row = tid >> 2, chunk = tid & 3;
      int node = n0 + row;
      if (node < N_NODES) {
        uint2 z = make_uint2(0, 0);
        *(uint2*)(h0 + (size_t)node * PAD_F + 48 + chunk * 4) = z;
      }
    }
  } else {
    // ======================= CSR path =======================
    const int b = blockIdx.x - MLP2_BLOCKS;
    const int t = tid;

    // inline exclusive prefix over bucket counts (196 entries)
    if (t < 256) bs[t] = (t < NBUCK) ? bcur[t * 16] : 0;
    __syncthreads();
    for (int off = 1; off < 256; off <<= 1) {
      int add = (t < 256 && t >= off) ? bs[t - off] : 0;
      __syncthreads();
      if (t < 256) bs[t] += add;
      __syncthreads();
    }
    const int n = bcur[b * 16];
    const int base = bs[b] - n;  // exclusive
    const size_t boff = (size_t)b * BCAP;
    if (b == 0 && t == 0) rowptr[N_NODES] = N_EDGES;

    cnt[t] = 0;
    __syncthreads();
    for (int i = t; i < n; i += 512)
      atomicAdd(&cnt[(int)((brec[boff + i] >> 17) & 511)], 1);
    __syncthreads();

    int v = cnt[t];
    sc[t] = v;
    __syncthreads();
    for (int off = 1; off < 512; off <<= 1) {
      int add = (t >= off) ? sc[t - off] : 0;
      __syncthreads();
      sc[t] += add;
      __syncthreads();
    }
    int excl = sc[t] - v;
    int grow = b * 512 + t;
    if (grow < N_NODES) rowptr[grow] = base + excl;
    cnt[t] = excl;
    __syncthreads();

    for (int i = t; i < n; i += 512) {
      u64 rec = brec[boff + i];
      int rr = (int)((rec >> 17) & 511);
      int p = atomicAdd(&cnt[rr], 1);
      edges[base + p] = rec & ROW_MASK_CLR;
    }
  }
}

// ---------------- propagation: wave/row, 8 edges x 8 lanes (dwordx4) -------
template <int FINAL>
__global__ __launch_bounds__(256) void prop_kernel(
    const __bf16* __restrict__ hin, __bf16* __restrict__ hout,
    float* __restrict__ fout, const int* __restrict__ rowptr,
    const u64* __restrict__ edges) {
  int wid = (blockIdx.x * 256 + threadIdx.x) >> 6;
  int lane = threadIdx.x & 63;
  if (wid >= N_NODES) return;
  const int g = lane >> 3;
  const int t = lane & 7;
  int s = __builtin_amdgcn_readfirstlane(rowptr[wid]);
  int e = __builtin_amdgcn_readfirstlane(rowptr[wid + 1]);

  float acc[8];
#pragma unroll
  for (int j = 0; j < 8; j++) acc[j] = 0.f;

  if (g == 0) {
    uint4 q = *(const uint4*)(hin + (size_t)wid * PAD_F + t * 8);
    unsigned uu[4] = {q.x, q.y, q.z, q.w};
#pragma unroll
    for (int k = 0; k < 4; k++) {
      acc[2 * k] = ALPHA * __uint_as_float(uu[k] << 16);
      acc[2 * k + 1] = ALPHA * __uint_as_float(uu[k] & 0xffff0000u);
    }
  }

  int i = s + g;
  for (; i + 8 < e; i += 16) {
    u64 r0 = edges[i];
    u64 r1 = edges[i + 8];
    int c0 = (int)(r0 & 0xffffffffu);
    int c1 = (int)(r1 & 0xffffffffu);
    float v0 = __uint_as_float((unsigned)(r0 >> 32));
    float v1 = __uint_as_float((unsigned)(r1 >> 32));
    uint4 q0 = *(const uint4*)(hin + (size_t)c0 * PAD_F + t * 8);
    uint4 q1 = *(const uint4*)(hin + (size_t)c1 * PAD_F + t * 8);
    unsigned a0[4] = {q0.x, q0.y, q0.z, q0.w};
    unsigned a1[4] = {q1.x, q1.y, q1.z, q1.w};
#pragma unroll
    for (int k = 0; k < 4; k++) {
      acc[2 * k] = fmaf(v0, __uint_as_float(a0[k] << 16), acc[2 * k]);
      acc[2 * k + 1] = fmaf(v0, __uint_as_float(a0[k] & 0xffff0000u), acc[2 * k + 1]);
    }
#pragma unroll
    for (int k = 0; k < 4; k++) {
      acc[2 * k] = fmaf(v1, __uint_as_float(a1[k] << 16), acc[2 * k]);
      acc[2 * k + 1] = fmaf(v1, __uint_as_float(a1[k] & 0xffff0000u), acc[2 * k + 1]);
    }
  }
  if (i < e) {
    u64 r0 = edges[i];
    int c0 = (int)(r0 & 0xffffffffu);
    float v0 = __uint_as_float((unsigned)(r0 >> 32));
    uint4 q0 = *(const uint4*)(hin + (size_t)c0 * PAD_F + t * 8);
    unsigned a0[4] = {q0.x, q0.y, q0.z, q0.w};
#pragma unroll
    for (int k = 0; k < 4; k++) {
      acc[2 * k] = fmaf(v0, __uint_as_float(a0[k] << 16), acc[2 * k]);
      acc[2 * k + 1] = fmaf(v0, __uint_as_float(a0[k] & 0xffff0000u), acc[2 * k + 1]);
    }
  }

#pragma unroll
  for (int m = 8; m <= 32; m <<= 1) {
#pragma unroll
    for (int j = 0; j < 8; j++) acc[j] += __shfl_xor(acc[j], m, 64);
  }

  if (g == 0) {
    if (FINAL) {
      if (t < 6) {
        float* dst = fout + (size_t)wid * OUT_F + t * 8;
        v4f lo4 = {acc[0], acc[1], acc[2], acc[3]};
        v4f hi4 = {acc[4], acc[5], acc[6], acc[7]};
        __builtin_nontemporal_store(lo4, (v4f*)dst);
        __builtin_nontemporal_store(hi4, (v4f*)(dst + 4));
      }
    } else {
      unsigned w[4];
#pragma unroll
      for (int k = 0; k < 4; k++) {
        unsigned short lo = __builtin_bit_cast(unsigned short, (__bf16)acc[2 * k]);
        unsigned short hi = __builtin_bit_cast(unsigned short, (__bf16)acc[2 * k + 1]);
        w[k] = ((unsigned)hi << 16) | lo;
      }
      *(uint4*)(hout + (size_t)wid * PAD_F + t * 8) =
          make_uint4(w[0], w[1], w[2], w[3]);
    }
  }
}

// ---------------- launch ----------------------------------------------------
extern "C" void kernel_launch(void* const* d_in, const int* in_sizes, int n_in,
                              void* d_out, int out_size, void* d_ws,
                              size_t ws_size, hipStream_t stream) {
  const float* x = (const float*)d_in[0];
  const int* rows = (const int*)d_in[1];
  const int* cols = (const int*)d_in[2];
  const float* vals = (const float*)d_in[3];
  const float* W1 = (const float*)d_in[4];
  const float* b1 = (const float*)d_in[5];
  const float* W2 = (const float*)d_in[6];
  const float* b2 = (const float*)d_in[7];
  float* out = (float*)d_out;

  char* ws = (char*)d_ws;
  const size_t HB_OFF = 0;                  // 12,800,000
  const size_t HA_OFF = 12800000;           // 12,800,000
  const size_t EDGES_OFF = 25600000;        // 12,800,000
  const size_t BREC_OFF = 38400000;         // 16,056,320
  const size_t ROWPTR_OFF = 54456320;       // 400,128
  const size_t BCUR_OFF = 54856448;         // 12,544
  const size_t W1T_OFF = 54870016;          // 65,536
  const size_t W2T_OFF = 54935552;          // 12,288  -> end 54,947,840

  __bf16* hA = (__bf16*)(ws + HA_OFF);
  __bf16* hB = (__bf16*)(ws + HB_OFF);
  u64* edges = (u64*)(ws + EDGES_OFF);
  u64* brec = (u64*)(ws + BREC_OFF);
  int* rowptr = (int*)(ws + ROWPTR_OFF);
  int* bcur = (int*)(ws + BCUR_OFF);
  __bf16* w1t = (__bf16*)(ws + W1T_OFF);
  __bf16* w2t = (__bf16*)(ws + W2T_OFF);

  (void)hipMemsetAsync(bcur, 0, NBUCK * 64, stream);

  pre_kernel<<<BUCKET_BLOCKS + CONVW_BLOCKS, 256, 0, stream>>>(
      W1, W2, w1t, w2t, rows, cols, vals, bcur, brec);

  fused_mlp_csr<<<MLP2_BLOCKS + NBUCK, 512, 0, stream>>>(
      x, w1t, b1, w2t, b2, hA, bcur, brec, rowptr, edges);

  const int PROP_BLOCKS = (N_NODES * 64 + 255) / 256;
  for (int k = 0; k < K_STEPS - 1; k++) {
    const __bf16* hin = (k & 1) ? hB : hA;
    __bf16* hout = (k & 1) ? hA : hB;
    prop_kernel<0><<<PROP_BLOCKS, 256, 0, stream>>>(hin, hout, nullptr, rowptr,
                                                    edges);
  }
  prop_kernel<1><<<PROP_BLOCKS, 256, 0, stream>>>(hB, nullptr, out, rowptr,
                                                  edges);
}

// Round 16
// 491.250 us; speedup vs baseline: 1.2187x; 1.0029x over previous
//
#include <hip/hip_runtime.h>

#define N_NODES 100000
#define N_EDGES 1600000
#define IN_F 256
#define HID 128
#define OUT_F 48
#define PAD_F 64
#define ALPHA 0.01f
#define K_STEPS 10
#define DROP_SCALE (1.0f / (1.0f + 1e-5f))

#define NBUCK 196      // buckets of 512 rows
#define BCAP 10240     // bucket capacity (mean 8163, 23 sigma headroom)
#define EPB 4096       // edges per bucketing block
#define ROW_MASK_CLR 0xFFFFFFFFFC01FFFFULL  // clears bits 25:17 (local row)

#define BUCKET_BLOCKS 391   // ceil(1.6M / 4096)
#define CONVW_BLOCKS 153    // (32768 + 6144 + 255)/256
#define MLP2_BLOCKS 391     // ceil(100000 / 256), 256 rows per 1024-thr block

typedef __bf16 v8bf __attribute__((ext_vector_type(8)));
typedef float v4f __attribute__((ext_vector_type(4)));
typedef unsigned long long u64;

static __device__ __forceinline__ __bf16 tobf(float f) { return (__bf16)f; }

// ---------------- dispatch 1: bucket binning + weight conv ------------------
// rec u64: val[63:32] | localrow[25:17] | col[16:0]
__global__ __launch_bounds__(256) void pre_kernel(
    const float* __restrict__ W1, const float* __restrict__ W2,
    __bf16* __restrict__ w1t, __bf16* __restrict__ w2t,
    const int* __restrict__ rows, const int* __restrict__ cols,
    const float* __restrict__ vals, int* __restrict__ bcur,
    u64* __restrict__ brec) {
  __shared__ int lhist[NBUCK];
  __shared__ int lbase[NBUCK];
  const int tid = threadIdx.x;

  if (blockIdx.x < BUCKET_BLOCKS) {
    const int base = blockIdx.x * EPB;

    for (int i = tid; i < NBUCK; i += 256) lhist[i] = 0;
    __syncthreads();

    u64 rec[16];
    short bb[16];
    short pp[16];
#pragma unroll
    for (int j = 0; j < 4; j++) {
      int e = base + j * 1024 + tid * 4;
      bool ok = e < N_EDGES;
      int4 r4 = ok ? *(const int4*)(rows + e) : make_int4(0, 0, 0, 0);
      int4 c4 = ok ? *(const int4*)(cols + e) : make_int4(0, 0, 0, 0);
      float4 v4 = ok ? *(const float4*)(vals + e) : make_float4(0, 0, 0, 0);
      int rr[4] = {r4.x, r4.y, r4.z, r4.w};
      int cc[4] = {c4.x, c4.y, c4.z, c4.w};
      float vv[4] = {v4.x, v4.y, v4.z, v4.w};
#pragma unroll
      for (int q = 0; q < 4; q++) {
        int idx = j * 4 + q;
        int b = rr[q] >> 9;
        float v = vv[q] * (DROP_SCALE * (1.0f - ALPHA));
        rec[idx] = ((u64)__float_as_uint(v) << 32) |
                   ((u64)(rr[q] & 511) << 17) | (unsigned)cc[q];
        bb[idx] = ok ? (short)b : (short)-1;
        pp[idx] = ok ? (short)atomicAdd(&lhist[b], 1) : (short)0;
      }
    }
    __syncthreads();

    for (int i = tid; i < NBUCK; i += 256) {
      int n = lhist[i];
      lbase[i] = (n > 0) ? atomicAdd(&bcur[i * 16], n) : 0;
    }
    __syncthreads();

#pragma unroll
    for (int j = 0; j < 16; j++) {
      if (bb[j] >= 0)
        brec[(size_t)bb[j] * BCAP + lbase[bb[j]] + pp[j]] = rec[j];
    }
  } else {
    // ---- weight transpose+convert ----
    int i = (blockIdx.x - BUCKET_BLOCKS) * 256 + tid;
    if (i < HID * IN_F) {
      int n = i >> 8, k = i & 255;
      w1t[i] = tobf(W1[k * HID + n]);
    }
    int j = i - HID * IN_F;
    if (j >= 0 && j < OUT_F * HID) {
      int n = j >> 7, k = j & 127;
      w2t[j] = tobf(W2[k * OUT_F + n]);
    }
  }
}

// ---------------- dispatch 2: MLP (1024 thr, full weights in LDS) + CSR -----
// 16 waves x 16 rows = 256 rows per block; w1+w2 staged ONCE per block
// (80 KB amortized over 16 waves); ~152 KB LDS -> 1 block/CU.
__global__ __launch_bounds__(1024, 1) void fused_mlp_csr(
    const float* __restrict__ x, const __bf16* __restrict__ w1t,
    const float* __restrict__ b1, const __bf16* __restrict__ w2t,
    const float* __restrict__ b2, __bf16* __restrict__ h0,
    const int* __restrict__ bcur, const u64* __restrict__ brec,
    int* __restrict__ rowptr, u64* __restrict__ edges) {
  __shared__ __bf16 w1s[128][264];  // 67.6 KB (full W1^T, +8 pad)
  __shared__ __bf16 h1s[256][136];  // 69.6 KB
  __shared__ __bf16 w2s[48][136];   // 13.1 KB
  __shared__ int bs[256];
  __shared__ int cnt[512];
  __shared__ int sc[512];
  // total ~152 KB -> 1 block/CU (160 KB budget)

  const int tid = threadIdx.x;

  if (blockIdx.x < MLP2_BLOCKS) {
    // ======================= MLP path =======================
    const int wv = tid >> 6;          // 0..15
    const int l = tid & 63;
    const int lm = l & 15;
    const int ko = (l >> 4) * 8;
    const int n0 = blockIdx.x * 256;
    const int nw = n0 + wv * 16;
    const int xrow = nw + lm;
    const int xrc = (xrow < N_NODES) ? xrow : (N_NODES - 1);  // clamp ragged
    const float* xrp = x + (size_t)xrc * IN_F + ko;

    // issue this lane's full x row (16 independent 16B loads)
    v4f xf[16];
#pragma unroll
    for (int k0 = 0; k0 < 8; k0++) {
      xf[2 * k0] = *(const v4f*)(xrp + k0 * 32);
      xf[2 * k0 + 1] = *(const v4f*)(xrp + k0 * 32 + 4);
    }

    // stage full w1t (4096 x 16B) + w2t (768 x 16B) once per block
    const uint4* w1src = (const uint4*)w1t;
    for (int i = tid; i < 4096; i += 1024)
      *(uint4*)&w1s[i >> 5][(i & 31) * 8] = w1src[i];
    const uint4* w2src = (const uint4*)w2t;
    for (int i = tid; i < 768; i += 1024)
      *(uint4*)&w2s[i >> 4][(i & 15) * 8] = w2src[i];
    __syncthreads();

    // convert fp32 -> bf16 A-frags
    v8bf a8[8];
#pragma unroll
    for (int k0 = 0; k0 < 8; k0++) {
#pragma unroll
      for (int j = 0; j < 8; j++) a8[k0][j] = tobf(xf[2 * k0 + (j >> 2)][j & 3]);
    }

    // layer 1: per wave [16 x 256] @ [256 x 128], B from LDS
    v4f acc1[8];
#pragma unroll
    for (int nf = 0; nf < 8; nf++) acc1[nf] = (v4f){0.f, 0.f, 0.f, 0.f};
#pragma unroll
    for (int k0 = 0; k0 < 8; k0++) {
#pragma unroll
      for (int nf = 0; nf < 8; nf++) {
        v8bf b = *(const v8bf*)&w1s[nf * 16 + lm][k0 * 32 + ko];
        acc1[nf] = __builtin_amdgcn_mfma_f32_16x16x32_bf16(a8[k0], b, acc1[nf], 0, 0, 0);
      }
    }

    // bias + relu -> h1s. D frag: col=lm, row=(l>>4)*4+q
#pragma unroll
    for (int nf = 0; nf < 8; nf++) {
      float bb = b1[nf * 16 + lm];
#pragma unroll
      for (int q = 0; q < 4; q++) {
        int rr = wv * 16 + (l >> 4) * 4 + q;
        h1s[rr][nf * 16 + lm] = tobf(fmaxf(acc1[nf][q] + bb, 0.f));
      }
    }
    __syncthreads();

    // layer 2: A from h1s, B from w2s (LDS)
    const int lrow = wv * 16 + lm;
    v4f acc2[3];
#pragma unroll
    for (int nf = 0; nf < 3; nf++) acc2[nf] = (v4f){0.f, 0.f, 0.f, 0.f};
#pragma unroll
    for (int k0 = 0; k0 < 4; k0++) {
      v8bf a = *(const v8bf*)&h1s[lrow][k0 * 32 + ko];
#pragma unroll
      for (int nf = 0; nf < 3; nf++) {
        v8bf b = *(const v8bf*)&w2s[nf * 16 + lm][k0 * 32 + ko];
        acc2[nf] = __builtin_amdgcn_mfma_f32_16x16x32_bf16(a, b, acc2[nf], 0, 0, 0);
      }
    }
#pragma unroll
    for (int nf = 0; nf < 3; nf++) {
      float bb = b2[nf * 16 + lm];
#pragma unroll
      for (int q = 0; q < 4; q++) {
        int node = nw + (l >> 4) * 4 + q;
        if (node < N_NODES)
          h0[(size_t)node * PAD_F + nf * 16 + lm] = tobf(acc2[nf][q] + bb);
      }
    }
    // zero pad cols 48..63: 256 rows x 4 uint2 chunks = 1024 = blockDim
    {
      int row = tid >> 2, chunk = tid & 3;
      int node = n0 + row;
      if (node < N_NODES) {
        uint2 z = make_uint2(0, 0);
        *(uint2*)(h0 + (size_t)node * PAD_F + 48 + chunk * 4) = z;
      }
    }
  } else {
    // ======================= CSR path (1024 thr) =======================
    const int b = blockIdx.x - MLP2_BLOCKS;
    const int t = tid;

    // inline exclusive prefix over bucket counts (196 entries, t<256 active)
    if (t < 256) bs[t] = (t < NBUCK) ? bcur[t * 16] : 0;
    __syncthreads();
    for (int off = 1; off < 256; off <<= 1) {
      int add = (t < 256 && t >= off) ? bs[t - off] : 0;
      __syncthreads();
      if (t < 256) bs[t] += add;
      __syncthreads();
    }
    const int n = bcur[b * 16];
    const int base = bs[b] - n;  // exclusive
    const size_t boff = (size_t)b * BCAP;
    if (b == 0 && t == 0) rowptr[N_NODES] = N_EDGES;

    if (t < 512) cnt[t] = 0;
    __syncthreads();
    for (int i = t; i < n; i += 1024)
      atomicAdd(&cnt[(int)((brec[boff + i] >> 17) & 511)], 1);
    __syncthreads();

    int v = (t < 512) ? cnt[t] : 0;
    if (t < 512) sc[t] = v;
    __syncthreads();
    for (int off = 1; off < 512; off <<= 1) {
      int add = (t < 512 && t >= off) ? sc[t - off] : 0;
      __syncthreads();
      if (t < 512) sc[t] += add;
      __syncthreads();
    }
    if (t < 512) {
      int excl = sc[t] - v;
      int grow = b * 512 + t;
      if (grow < N_NODES) rowptr[grow] = base + excl;
      cnt[t] = excl;
    }
    __syncthreads();

    for (int i = t; i < n; i += 1024) {
      u64 rec = brec[boff + i];
      int rr = (int)((rec >> 17) & 511);
      int p = atomicAdd(&cnt[rr], 1);
      edges[base + p] = rec & ROW_MASK_CLR;
    }
  }
}

// ---------------- propagation: wave/row, 8 edges x 8 lanes (dwordx4) -------
template <int FINAL>
__global__ __launch_bounds__(256) void prop_kernel(
    const __bf16* __restrict__ hin, __bf16* __restrict__ hout,
    float* __restrict__ fout, const int* __restrict__ rowptr,
    const u64* __restrict__ edges) {
  int wid = (blockIdx.x * 256 + threadIdx.x) >> 6;
  int lane = threadIdx.x & 63;
  if (wid >= N_NODES) return;
  const int g = lane >> 3;
  const int t = lane & 7;
  int s = __builtin_amdgcn_readfirstlane(rowptr[wid]);
  int e = __builtin_amdgcn_readfirstlane(rowptr[wid + 1]);

  float acc[8];
#pragma unroll
  for (int j = 0; j < 8; j++) acc[j] = 0.f;

  if (g == 0) {
    uint4 q = *(const uint4*)(hin + (size_t)wid * PAD_F + t * 8);
    unsigned uu[4] = {q.x, q.y, q.z, q.w};
#pragma unroll
    for (int k = 0; k < 4; k++) {
      acc[2 * k] = ALPHA * __uint_as_float(uu[k] << 16);
      acc[2 * k + 1] = ALPHA * __uint_as_float(uu[k] & 0xffff0000u);
    }
  }

  int i = s + g;
  for (; i + 8 < e; i += 16) {
    u64 r0 = edges[i];
    u64 r1 = edges[i + 8];
    int c0 = (int)(r0 & 0xffffffffu);
    int c1 = (int)(r1 & 0xffffffffu);
    float v0 = __uint_as_float((unsigned)(r0 >> 32));
    float v1 = __uint_as_float((unsigned)(r1 >> 32));
    uint4 q0 = *(const uint4*)(hin + (size_t)c0 * PAD_F + t * 8);
    uint4 q1 = *(const uint4*)(hin + (size_t)c1 * PAD_F + t * 8);
    unsigned a0[4] = {q0.x, q0.y, q0.z, q0.w};
    unsigned a1[4] = {q1.x, q1.y, q1.z, q1.w};
#pragma unroll
    for (int k = 0; k < 4; k++) {
      acc[2 * k] = fmaf(v0, __uint_as_float(a0[k] << 16), acc[2 * k]);
      acc[2 * k + 1] = fmaf(v0, __uint_as_float(a0[k] & 0xffff0000u), acc[2 * k + 1]);
    }
#pragma unroll
    for (int k = 0; k < 4; k++) {
      acc[2 * k] = fmaf(v1, __uint_as_float(a1[k] << 16), acc[2 * k]);
      acc[2 * k + 1] = fmaf(v1, __uint_as_float(a1[k] & 0xffff0000u), acc[2 * k + 1]);
    }
  }
  if (i < e) {
    u64 r0 = edges[i];
    int c0 = (int)(r0 & 0xffffffffu);
    float v0 = __uint_as_float((unsigned)(r0 >> 32));
    uint4 q0 = *(const uint4*)(hin + (size_t)c0 * PAD_F + t * 8);
    unsigned a0[4] = {q0.x, q0.y, q0.z, q0.w};
#pragma unroll
    for (int k = 0; k < 4; k++) {
      acc[2 * k] = fmaf(v0, __uint_as_float(a0[k] << 16), acc[2 * k]);
      acc[2 * k + 1] = fmaf(v0, __uint_as_float(a0[k] & 0xffff0000u), acc[2 * k + 1]);
    }
  }

#pragma unroll
  for (int m = 8; m <= 32; m <<= 1) {
#pragma unroll
    for (int j = 0; j < 8; j++) acc[j] += __shfl_xor(acc[j], m, 64);
  }

  if (g == 0) {
    if (FINAL) {
      if (t < 6) {
        float* dst = fout + (size_t)wid * OUT_F + t * 8;
        v4f lo4 = {acc[0], acc[1], acc[2], acc[3]};
        v4f hi4 = {acc[4], acc[5], acc[6], acc[7]};
        __builtin_nontemporal_store(lo4, (v4f*)dst);
        __builtin_nontemporal_store(hi4, (v4f*)(dst + 4));
      }
    } else {
      unsigned w[4];
#pragma unroll
      for (int k = 0; k < 4; k++) {
        unsigned short lo = __builtin_bit_cast(unsigned short, (__bf16)acc[2 * k]);
        unsigned short hi = __builtin_bit_cast(unsigned short, (__bf16)acc[2 * k + 1]);
        w[k] = ((unsigned)hi << 16) | lo;
      }
      *(uint4*)(hout + (size_t)wid * PAD_F + t * 8) =
          make_uint4(w[0], w[1], w[2], w[3]);
    }
  }
}

// ---------------- launch ----------------------------------------------------
extern "C" void kernel_launch(void* const* d_in, const int* in_sizes, int n_in,
                              void* d_out, int out_size, void* d_ws,
                              size_t ws_size, hipStream_t stream) {
  const float* x = (const float*)d_in[0];
  const int* rows = (const int*)d_in[1];
  const int* cols = (const int*)d_in[2];
  const float* vals = (const float*)d_in[3];
  const float* W1 = (const float*)d_in[4];
  const float* b1 = (const float*)d_in[5];
  const float* W2 = (const float*)d_in[6];
  const float* b2 = (const float*)d_in[7];
  float* out = (float*)d_out;

  char* ws = (char*)d_ws;
  const size_t HB_OFF = 0;                  // 12,800,000
  const size_t HA_OFF = 12800000;           // 12,800,000
  const size_t EDGES_OFF = 25600000;        // 12,800,000
  const size_t BREC_OFF = 38400000;         // 16,056,320
  const size_t ROWPTR_OFF = 54456320;       // 400,128
  const size_t BCUR_OFF = 54856448;         // 12,544
  const size_t W1T_OFF = 54870016;          // 65,536
  const size_t W2T_OFF = 54935552;          // 12,288  -> end 54,947,840

  __bf16* hA = (__bf16*)(ws + HA_OFF);
  __bf16* hB = (__bf16*)(ws + HB_OFF);
  u64* edges = (u64*)(ws + EDGES_OFF);
  u64* brec = (u64*)(ws + BREC_OFF);
  int* rowptr = (int*)(ws + ROWPTR_OFF);
  int* bcur = (int*)(ws + BCUR_OFF);
  __bf16* w1t = (__bf16*)(ws + W1T_OFF);
  __bf16* w2t = (__bf16*)(ws + W2T_OFF);

  (void)hipMemsetAsync(bcur, 0, NBUCK * 64, stream);

  pre_kernel<<<BUCKET_BLOCKS + CONVW_BLOCKS, 256, 0, stream>>>(
      W1, W2, w1t, w2t, rows, cols, vals, bcur, brec);

  fused_mlp_csr<<<MLP2_BLOCKS + NBUCK, 1024, 0, stream>>>(
      x, w1t, b1, w2t, b2, hA, bcur, brec, rowptr, edges);

  const int PROP_BLOCKS = (N_NODES * 64 + 255) / 256;
  for (int k = 0; k < K_STEPS - 1; k++) {
    const __bf16* hin = (k & 1) ? hB : hA;
    __bf16* hout = (k & 1) ? hA : hB;
    prop_kernel<0><<<PROP_BLOCKS, 256, 0, stream>>>(hin, hout, nullptr, rowptr,
                                                    edges);
  }
  prop_kernel<1><<<PROP_BLOCKS, 256, 0, stream>>>(hB, nullptr, out, rowptr,
                                                  edges);
}